// Round 1
// baseline (2024.110 us; speedup 1.0000x reference)
//
#include <hip/hip_runtime.h>
#include <hip/hip_bf16.h>

#define NS_N 4000
#define NT_N 4096
#define ES_E 64000
#define ET_E 65536
#define D_IN 128
#define D_H 256
#define CAT_D 896   // 128 + 3*256
#define ALPHA_F 20.0f
#define EPS_F 1e-10f

// ---------------- GEMM: C[M,N] = A[M,K](lda) @ B[K,N] (+bias) ----------------
__global__ __launch_bounds__(256) void gemm_nn_kernel(
    const float* __restrict__ A, const float* __restrict__ B,
    const float* __restrict__ bias, float* __restrict__ C,
    int M, int K, int N, int lda, int ldc)
{
    __shared__ float As[16][65];
    __shared__ float Bs[16][65];
    const int bm = blockIdx.x * 64;
    const int bn = blockIdx.y * 64;
    const int tid = threadIdx.x;
    const int tx = tid & 15, ty = tid >> 4;
    float acc[4][4] = {};
    for (int k0 = 0; k0 < K; k0 += 16) {
        #pragma unroll
        for (int t = 0; t < 4; ++t) {
            int idx = tid + t * 256;          // 0..1023
            int m = idx >> 4, kk = idx & 15;  // consecutive tid -> consecutive kk (coalesced rows)
            int gm = bm + m;
            As[kk][m] = (gm < M) ? A[(size_t)gm * lda + k0 + kk] : 0.f;
        }
        #pragma unroll
        for (int t = 0; t < 4; ++t) {
            int idx = tid + t * 256;
            int kk = idx >> 6, n = idx & 63;  // consecutive tid -> consecutive n (coalesced)
            int gn = bn + n;
            Bs[kk][n] = (gn < N) ? B[(size_t)(k0 + kk) * N + gn] : 0.f;
        }
        __syncthreads();
        #pragma unroll
        for (int kk = 0; kk < 16; ++kk) {
            float a[4], b[4];
            #pragma unroll
            for (int i = 0; i < 4; ++i) a[i] = As[kk][ty * 4 + i];
            #pragma unroll
            for (int j = 0; j < 4; ++j) b[j] = Bs[kk][tx * 4 + j];
            #pragma unroll
            for (int i = 0; i < 4; ++i)
                #pragma unroll
                for (int j = 0; j < 4; ++j)
                    acc[i][j] += a[i] * b[j];
        }
        __syncthreads();
    }
    #pragma unroll
    for (int i = 0; i < 4; ++i) {
        int gm = bm + ty * 4 + i;
        if (gm >= M) continue;
        #pragma unroll
        for (int j = 0; j < 4; ++j) {
            int gn = bn + tx * 4 + j;
            if (gn >= N) continue;
            float v = acc[i][j];
            if (bias) v += bias[gn];
            C[(size_t)gm * ldc + gn] = v;
        }
    }
}

// ---------- GEMM NT with exp epilogue: C = exp(ALPHA*(A@B^T + EPS)) ----------
// A[M,K] row-major, B[N,K] row-major, C[M?,ldc]
__global__ __launch_bounds__(256) void gemm_nt_exp_kernel(
    const float* __restrict__ A, const float* __restrict__ B,
    float* __restrict__ C, int M, int N, int K, int ldc)
{
    __shared__ float As[16][65];
    __shared__ float Bs[16][65];
    const int bm = blockIdx.x * 64;
    const int bn = blockIdx.y * 64;
    const int tid = threadIdx.x;
    const int tx = tid & 15, ty = tid >> 4;
    float acc[4][4] = {};
    for (int k0 = 0; k0 < K; k0 += 16) {
        #pragma unroll
        for (int t = 0; t < 4; ++t) {
            int idx = tid + t * 256;
            int m = idx >> 4, kk = idx & 15;
            int gm = bm + m;
            As[kk][m] = (gm < M) ? A[(size_t)gm * K + k0 + kk] : 0.f;
        }
        #pragma unroll
        for (int t = 0; t < 4; ++t) {
            int idx = tid + t * 256;
            int n = idx >> 4, kk = idx & 15;
            int gn = bn + n;
            Bs[kk][n] = (gn < N) ? B[(size_t)gn * K + k0 + kk] : 0.f;
        }
        __syncthreads();
        #pragma unroll
        for (int kk = 0; kk < 16; ++kk) {
            float a[4], b[4];
            #pragma unroll
            for (int i = 0; i < 4; ++i) a[i] = As[kk][ty * 4 + i];
            #pragma unroll
            for (int j = 0; j < 4; ++j) b[j] = Bs[kk][tx * 4 + j];
            #pragma unroll
            for (int i = 0; i < 4; ++i)
                #pragma unroll
                for (int j = 0; j < 4; ++j)
                    acc[i][j] += a[i] * b[j];
        }
        __syncthreads();
    }
    #pragma unroll
    for (int i = 0; i < 4; ++i) {
        int gm = bm + ty * 4 + i;
        if (gm >= M) continue;
        #pragma unroll
        for (int j = 0; j < 4; ++j) {
            int gn = bn + tx * 4 + j;
            if (gn >= N) continue;
            C[(size_t)gm * ldc + gn] = expf(ALPHA_F * (acc[i][j] + EPS_F));
        }
    }
}

// fill rows [rbeg, rend) of s0 with constant v
__global__ void fill_rows_kernel(float* __restrict__ p, float v, size_t n)
{
    size_t i = (size_t)blockIdx.x * 256 + threadIdx.x;
    if (i < n) p[i] = v;
}

__global__ void fill_kernel(float* __restrict__ p, float v, int n)
{
    int i = blockIdx.x * 256 + threadIdx.x;
    if (i < n) p[i] = v;
}

// cat[i, 0:128] = x[i, :]
__global__ void copy_x_kernel(const float* __restrict__ x, float* __restrict__ cat, int N)
{
    int i = blockIdx.x, d = threadIdx.x;  // 128 threads
    if (i < N) cat[(size_t)i * CAT_D + d] = x[(size_t)i * D_IN + d];
}

__global__ void count_kernel(const int* __restrict__ idx, int* __restrict__ cnt, int E)
{
    int e = blockIdx.x * 256 + threadIdx.x;
    if (e < E) atomicAdd(&cnt[idx[e]], 1);
}

// out[bidx[e], :] += vals[aidx[e], :]
__global__ __launch_bounds__(256) void scatter_add_kernel(
    const float* __restrict__ vals, const int* __restrict__ aidx,
    const int* __restrict__ bidx, float* __restrict__ out, int E)
{
    int e = blockIdx.x;
    int d = threadIdx.x;
    if (e < E) {
        int a = aidx[e], b = bidx[e];
        atomicAdd(&out[(size_t)b * D_H + d], vals[(size_t)a * D_H + d]);
    }
}

// h_new = relu(root + br + agg1/cnt1 + agg2/cnt2) -> cat slice (ld CAT_D)
__global__ __launch_bounds__(256) void combine_relu_kernel(
    const float* __restrict__ root, const float* __restrict__ br,
    const float* __restrict__ agg1, const int* __restrict__ cnt1,
    const float* __restrict__ agg2, const int* __restrict__ cnt2,
    float* __restrict__ out, int N)
{
    int i = blockIdx.x, d = threadIdx.x;
    if (i >= N) return;
    float c1 = (float)max(cnt1[i], 1);
    float c2 = (float)max(cnt2[i], 1);
    size_t o = (size_t)i * D_H + d;
    float v = root[o] + br[d] + agg1[o] / c1 + agg2[o] / c2;
    out[(size_t)i * CAT_D + d] = fmaxf(v, 0.f);
}

// row L2 normalization, 256 threads per row
__global__ __launch_bounds__(256) void l2norm_kernel(
    const float* __restrict__ in, float* __restrict__ out, int N)
{
    int i = blockIdx.x, d = threadIdx.x;
    float v = in[(size_t)i * D_H + d];
    float s = v * v;
    #pragma unroll
    for (int off = 32; off; off >>= 1) s += __shfl_down(s, off);
    __shared__ float ws[4];
    if ((d & 63) == 0) ws[d >> 6] = s;
    __syncthreads();
    float tot = ws[0] + ws[1] + ws[2] + ws[3];
    out[(size_t)i * D_H + d] = v / fmaxf(sqrtf(tot), 1e-12f);
}

// tsum[j] += sum over row chunk of r[i]*s0[i][j]
__global__ __launch_bounds__(256) void colsum_kernel(
    const float* __restrict__ s0, const float* __restrict__ r, float* __restrict__ tsum)
{
    int j = blockIdx.x * 256 + threadIdx.x;
    int i0 = blockIdx.y * 128;
    float s = 0.f;
    for (int i = i0; i < i0 + 128; ++i)
        s += r[i] * s0[(size_t)i * NT_N + j];
    atomicAdd(&tsum[j], s);
}

__global__ void recip_kernel(const float* __restrict__ tsum, float* __restrict__ c)
{
    int j = blockIdx.x * 256 + threadIdx.x;
    if (j < NT_N) c[j] = 1.f / tsum[j];
}

// r[i] = 1 / sum_j s0[i][j]*c[j]
__global__ __launch_bounds__(256) void rowsum_kernel(
    const float* __restrict__ s0, const float* __restrict__ c, float* __restrict__ r)
{
    int i = blockIdx.x;
    float s = 0.f;
    for (int j = threadIdx.x; j < NT_N; j += 256)
        s += s0[(size_t)i * NT_N + j] * c[j];
    #pragma unroll
    for (int off = 32; off; off >>= 1) s += __shfl_down(s, off);
    __shared__ float ws[4];
    if ((threadIdx.x & 63) == 0) ws[threadIdx.x >> 6] = s;
    __syncthreads();
    if (threadIdx.x == 0) r[i] = 1.f / (ws[0] + ws[1] + ws[2] + ws[3]);
}

// out[i][j] = r[i]*s0[i][j]*c[j], i < NS
__global__ void output_kernel(const float* __restrict__ s0, const float* __restrict__ r,
                              const float* __restrict__ c, float* __restrict__ out)
{
    size_t idx = (size_t)blockIdx.x * 256 + threadIdx.x;
    if (idx < (size_t)NS_N * NT_N) {
        int i = (int)(idx >> 12);
        int j = (int)(idx & 4095);
        out[idx] = r[i] * s0[idx] * c[j];
    }
}

extern "C" void kernel_launch(void* const* d_in, const int* in_sizes, int n_in,
                              void* d_out, int out_size, void* d_ws, size_t ws_size,
                              hipStream_t stream)
{
    const float* x_s = (const float*)d_in[0];
    const float* x_t = (const float*)d_in[1];
    const int* edges = (const int*)d_in[2];
    const int* edget = (const int*)d_in[3];
    const float* W1[3] = {(const float*)d_in[4], (const float*)d_in[8], (const float*)d_in[12]};
    const float* W2[3] = {(const float*)d_in[5], (const float*)d_in[9], (const float*)d_in[13]};
    const float* Wr[3] = {(const float*)d_in[6], (const float*)d_in[10], (const float*)d_in[14]};
    const float* br[3] = {(const float*)d_in[7], (const float*)d_in[11], (const float*)d_in[15]};
    const float* final_w = (const float*)d_in[16];
    const float* final_b = (const float*)d_in[17];
    float* out = (float*)d_out;

    // workspace layout (floats)
    float* W = (float*)d_ws;
    size_t off = 0;
    float* S0   = W + off; off += (size_t)NT_N * NT_N;
    float* CATS = W + off; off += (size_t)NS_N * CAT_D;
    float* CATT = W + off; off += (size_t)NT_N * CAT_D;
    float* TMP1 = W + off; off += (size_t)NT_N * D_H;
    float* TMP2 = W + off; off += (size_t)NT_N * D_H;
    float* ROOT = W + off; off += (size_t)NT_N * D_H;
    float* AGG1 = W + off; off += (size_t)NT_N * D_H;
    float* AGG2 = W + off; off += (size_t)NT_N * D_H;
    float* HFIN = W + off; off += (size_t)NT_N * D_H;
    float* HNS  = W + off; off += (size_t)NS_N * D_H;
    float* HNT  = W + off; off += (size_t)NT_N * D_H;
    float* RVEC = W + off; off += NT_N;
    float* CVEC = W + off; off += NT_N;
    float* TSUM = W + off; off += NT_N;
    int* CNTA   = (int*)(W + off); off += NT_N;
    int* CNTB   = (int*)(W + off); off += NT_N;

    const int fan[3] = {D_IN, D_H, D_H};
    const int cat_off[4] = {0, 128, 384, 640};

    // ---- run one RelCNN per graph ----
    for (int g = 0; g < 2; ++g) {
        const int N = (g == 0) ? NS_N : NT_N;
        const int E = (g == 0) ? ES_E : ET_E;
        const float* x = (g == 0) ? x_s : x_t;
        const int* src = (g == 0) ? edges : edget;
        const int* dst = src + E;
        float* CAT = (g == 0) ? CATS : CATT;
        float* HN = (g == 0) ? HNS : HNT;

        copy_x_kernel<<<N, 128, 0, stream>>>(x, CAT, N);

        hipMemsetAsync(CNTA, 0, NT_N * sizeof(int), stream);
        hipMemsetAsync(CNTB, 0, NT_N * sizeof(int), stream);
        count_kernel<<<(E + 255) / 256, 256, 0, stream>>>(dst, CNTA, E); // dst-counts
        count_kernel<<<(E + 255) / 256, 256, 0, stream>>>(src, CNTB, E); // src-counts

        for (int l = 0; l < 3; ++l) {
            const float* h = CAT + cat_off[l];
            int K = fan[l];
            dim3 gg((N + 63) / 64, 4);
            gemm_nn_kernel<<<gg, 256, 0, stream>>>(h, W1[l], nullptr, TMP1, N, K, D_H, CAT_D, D_H);
            gemm_nn_kernel<<<gg, 256, 0, stream>>>(h, W2[l], nullptr, TMP2, N, K, D_H, CAT_D, D_H);
            gemm_nn_kernel<<<gg, 256, 0, stream>>>(h, Wr[l], nullptr, ROOT, N, K, D_H, CAT_D, D_H);
            hipMemsetAsync(AGG1, 0, (size_t)N * D_H * sizeof(float), stream);
            hipMemsetAsync(AGG2, 0, (size_t)N * D_H * sizeof(float), stream);
            scatter_add_kernel<<<E, 256, 0, stream>>>(TMP1, src, dst, AGG1, E);
            scatter_add_kernel<<<E, 256, 0, stream>>>(TMP2, dst, src, AGG2, E);
            combine_relu_kernel<<<N, 256, 0, stream>>>(ROOT, br[l], AGG1, CNTA, AGG2, CNTB,
                                                       CAT + cat_off[l + 1], N);
        }
        // final linear + l2norm
        dim3 gf((N + 63) / 64, 4);
        gemm_nn_kernel<<<gf, 256, 0, stream>>>(CAT, final_w, final_b, HFIN, N, CAT_D, D_H, CAT_D, D_H);
        l2norm_kernel<<<N, 256, 0, stream>>>(HFIN, HN, N);
    }

    // ---- match matrix: s0 = exp(ALPHA*(HNS @ HNT^T + EPS)), dummy rows const ----
    {
        dim3 gm((NS_N + 63) / 64, NT_N / 64);
        gemm_nt_exp_kernel<<<gm, 256, 0, stream>>>(HNS, HNT, S0, NS_N, NT_N, D_H, NT_N);
        size_t dn = (size_t)(NT_N - NS_N) * NT_N;
        float dummy = expf(ALPHA_F * (EPS_F + EPS_F));
        fill_rows_kernel<<<(int)((dn + 255) / 256), 256, 0, stream>>>(
            S0 + (size_t)NS_N * NT_N, dummy, dn);
    }

    // ---- Sinkhorn: factorized r/c iterations ----
    fill_kernel<<<NT_N / 256, 256, 0, stream>>>(RVEC, 1.f, NT_N);
    fill_kernel<<<NT_N / 256, 256, 0, stream>>>(CVEC, 1.f, NT_N);
    for (int it = 0; it < 10; ++it) {
        if ((it % 2) == 0) {
            // column normalization: c_j = 1 / sum_i r_i * s0_ij
            hipMemsetAsync(TSUM, 0, NT_N * sizeof(float), stream);
            dim3 gc(NT_N / 256, 32);
            colsum_kernel<<<gc, 256, 0, stream>>>(S0, RVEC, TSUM);
            recip_kernel<<<NT_N / 256, 256, 0, stream>>>(TSUM, CVEC);
        } else {
            // row normalization: r_i = 1 / sum_j s0_ij * c_j
            rowsum_kernel<<<NT_N, 256, 0, stream>>>(S0, CVEC, RVEC);
        }
    }

    // ---- output ----
    size_t total = (size_t)NS_N * NT_N;
    output_kernel<<<(int)((total + 255) / 256), 256, 0, stream>>>(S0, RVEC, CVEC, out);
}

// Round 2
// 994.776 us; speedup vs baseline: 2.0347x; 2.0347x over previous
//
#include <hip/hip_runtime.h>
#include <hip/hip_bf16.h>

#define NS_N 4000
#define NT_N 4096
#define NTOT (NS_N + NT_N)      // 8096
#define ES_E 64000
#define ET_E 65536
#define ETOT (ES_E + ET_E)      // 129536
#define D_IN 128
#define D_H 256
#define CAT_D 896               // 128 + 3*256
#define TMP_D 768               // 3*256 fused layer GEMM output
#define ALPHA_F 20.0f
#define EPS_F 1e-10f

// ---------------------------------------------------------------------------
// Templated fp32 GEMM. C[M,N] = A[M,K](lda) @ B (+bias) (+exp epilogue).
// NT_B=false: B is [K,N] row-major (ldb=N). NT_B=true: B is [N,K] (ldb=K).
// 256 threads as 16x16; per-thread tile TMxTN with split halves so all LDS
// reads are float4 at tx*4 / ty*4 (2-way bank aliasing = free).
// ---------------------------------------------------------------------------
template<int BM, int BN, bool NT_B, bool BIAS, bool EXP_EP>
__global__ __launch_bounds__(256) void sgemm_kernel(
    const float* __restrict__ A, const float* __restrict__ B,
    const float* __restrict__ bias, float* __restrict__ C,
    int M, int N, int K, int lda, int ldb, int ldc)
{
    constexpr int BK = 16;
    constexpr int TM = BM / 16;       // 4 or 8
    constexpr int TN = BN / 16;       // 8
    constexpr int RH = TM / 4;        // row halves
    constexpr int CH = TN / 4;        // col halves
    __shared__ float As[BK][BM + 4];
    __shared__ float Bs[BK][BN + 4];
    const int bm = blockIdx.x * BM;
    const int bn = blockIdx.y * BN;
    const int tid = threadIdx.x;
    const int tx = tid & 15, ty = tid >> 4;
    float acc[TM][TN] = {};

    for (int k0 = 0; k0 < K; k0 += BK) {
        #pragma unroll
        for (int t = 0; t < (BM * BK) / 256; ++t) {
            int idx = tid + t * 256;
            int m = idx >> 4, kk = idx & 15;
            int gm = bm + m;
            As[kk][m] = (gm < M) ? A[(size_t)gm * lda + k0 + kk] : 0.f;
        }
        #pragma unroll
        for (int t = 0; t < (BN * BK) / 256; ++t) {
            int idx = tid + t * 256;
            if (NT_B) {
                int n = idx >> 4, kk = idx & 15;
                int gn = bn + n;
                Bs[kk][n] = (gn < N) ? B[(size_t)gn * ldb + k0 + kk] : 0.f;
            } else {
                int kk = idx / BN, n = idx % BN;
                int gn = bn + n;
                Bs[kk][n] = (gn < N) ? B[(size_t)(k0 + kk) * ldb + gn] : 0.f;
            }
        }
        __syncthreads();
        #pragma unroll
        for (int kk = 0; kk < BK; ++kk) {
            float a[TM], b[TN];
            #pragma unroll
            for (int h = 0; h < RH; ++h) {
                const float4 v = *reinterpret_cast<const float4*>(&As[kk][h * (BM / 2) + ty * 4]);
                a[h * 4 + 0] = v.x; a[h * 4 + 1] = v.y; a[h * 4 + 2] = v.z; a[h * 4 + 3] = v.w;
            }
            #pragma unroll
            for (int h = 0; h < CH; ++h) {
                const float4 v = *reinterpret_cast<const float4*>(&Bs[kk][h * (BN / 2) + tx * 4]);
                b[h * 4 + 0] = v.x; b[h * 4 + 1] = v.y; b[h * 4 + 2] = v.z; b[h * 4 + 3] = v.w;
            }
            #pragma unroll
            for (int i = 0; i < TM; ++i)
                #pragma unroll
                for (int j = 0; j < TN; ++j)
                    acc[i][j] += a[i] * b[j];
        }
        __syncthreads();
    }
    #pragma unroll
    for (int hi = 0; hi < RH; ++hi) {
        #pragma unroll
        for (int ii = 0; ii < 4; ++ii) {
            int gm = bm + hi * (BM / 2) + ty * 4 + ii;
            if (gm >= M) continue;
            #pragma unroll
            for (int hj = 0; hj < CH; ++hj) {
                #pragma unroll
                for (int jj = 0; jj < 4; ++jj) {
                    int gn = bn + hj * (BN / 2) + tx * 4 + jj;
                    if (gn >= N) continue;
                    float v = acc[hi * 4 + ii][hj * 4 + jj];
                    if (BIAS) v += bias[gn];
                    if (EXP_EP) v = expf(ALPHA_F * (v + EPS_F));
                    C[(size_t)gm * ldc + gn] = v;
                }
            }
        }
    }
}

// ---------------------------------------------------------------------------
// CSR build: counts -> single-block scan -> cursor fill
// ---------------------------------------------------------------------------
__global__ void count_kernel(const int* __restrict__ idx, int off, int* __restrict__ cnt, int E)
{
    int e = blockIdx.x * 256 + threadIdx.x;
    if (e < E) atomicAdd(&cnt[idx[e] + off], 1);
}

__global__ __launch_bounds__(256) void scan_kernel(const int* __restrict__ cnt,
                                                   int* __restrict__ rowptr, int n)
{
    __shared__ int sums[256];
    const int t = threadIdx.x;
    const int per = (n + 255) / 256;
    const int lo = t * per, hi = min((t + 1) * per, n);
    int s = 0;
    for (int i = lo; i < hi; ++i) s += cnt[i];
    sums[t] = s;
    __syncthreads();
    for (int off = 1; off < 256; off <<= 1) {
        int v = (t >= off) ? sums[t - off] : 0;
        __syncthreads();
        sums[t] += v;
        __syncthreads();
    }
    int base = (t == 0) ? 0 : sums[t - 1];
    for (int i = lo; i < hi; ++i) { rowptr[i] = base; base += cnt[i]; }
    if (t == 255) rowptr[n] = base;
}

__global__ void fill_csr_kernel(const int* __restrict__ key, const int* __restrict__ val,
                                int off, int* __restrict__ cur, int* __restrict__ col, int E)
{
    int e = blockIdx.x * 256 + threadIdx.x;
    if (e < E) {
        int pos = atomicAdd(&cur[key[e] + off], 1);
        col[pos] = val[e] + off;
    }
}

// ---------------------------------------------------------------------------
// weight concat: WC[K][768] = [W1 | W2 | Wr]
// ---------------------------------------------------------------------------
__global__ void wcat_kernel(const float* __restrict__ W1, const float* __restrict__ W2,
                            const float* __restrict__ Wr, float* __restrict__ WC, int K)
{
    int idx = blockIdx.x * 256 + threadIdx.x;
    if (idx < K * TMP_D) {
        int k = idx / TMP_D, c = idx % TMP_D;
        float v = (c < 256) ? W1[k * 256 + c]
                : (c < 512) ? W2[k * 256 + (c - 256)]
                            : Wr[k * 256 + (c - 512)];
        WC[idx] = v;
    }
}

// cat[i, 0:128] = x[i, :]  (combined graphs)
__global__ void copy_x_kernel(const float* __restrict__ xs, const float* __restrict__ xt,
                              float* __restrict__ CAT)
{
    int i = blockIdx.x, d = threadIdx.x;  // 128 threads
    const float* x = (i < NS_N) ? &xs[(size_t)i * D_IN] : &xt[(size_t)(i - NS_N) * D_IN];
    CAT[(size_t)i * CAT_D + d] = x[d];
}

// ---------------------------------------------------------------------------
// gather + mean + root + bias + relu, one 64-lane wave per node (float4/lane)
// TMP cols: [0:256)=h@W1, [256:512)=h@W2, [512:768)=h@Wr
// ---------------------------------------------------------------------------
__global__ __launch_bounds__(256) void gather_combine_kernel(
    const float* __restrict__ TMP,
    const int* __restrict__ rp_in, const int* __restrict__ ci_in,
    const int* __restrict__ rp_out, const int* __restrict__ ci_out,
    const float* __restrict__ br, float* __restrict__ CAT, int catoff)
{
    int node = blockIdx.x * 4 + (threadIdx.x >> 6);
    if (node >= NTOT) return;
    int d = (threadIdx.x & 63) * 4;

    float4 a1 = make_float4(0.f, 0.f, 0.f, 0.f);
    int b0 = rp_in[node], e0 = rp_in[node + 1];
    for (int e = b0; e < e0; ++e) {
        const float4 v = *reinterpret_cast<const float4*>(&TMP[(size_t)ci_in[e] * TMP_D + d]);
        a1.x += v.x; a1.y += v.y; a1.z += v.z; a1.w += v.w;
    }
    float s1 = 1.f / (float)max(e0 - b0, 1);

    float4 a2 = make_float4(0.f, 0.f, 0.f, 0.f);
    int b1 = rp_out[node], e1 = rp_out[node + 1];
    for (int e = b1; e < e1; ++e) {
        const float4 v = *reinterpret_cast<const float4*>(&TMP[(size_t)ci_out[e] * TMP_D + 256 + d]);
        a2.x += v.x; a2.y += v.y; a2.z += v.z; a2.w += v.w;
    }
    float s2 = 1.f / (float)max(e1 - b1, 1);

    const float4 rt = *reinterpret_cast<const float4*>(&TMP[(size_t)node * TMP_D + 512 + d]);
    const float4 bb = *reinterpret_cast<const float4*>(&br[d]);
    float4 o;
    o.x = fmaxf(rt.x + bb.x + a1.x * s1 + a2.x * s2, 0.f);
    o.y = fmaxf(rt.y + bb.y + a1.y * s1 + a2.y * s2, 0.f);
    o.z = fmaxf(rt.z + bb.z + a1.z * s1 + a2.z * s2, 0.f);
    o.w = fmaxf(rt.w + bb.w + a1.w * s1 + a2.w * s2, 0.f);
    *reinterpret_cast<float4*>(&CAT[(size_t)node * CAT_D + catoff + d]) = o;
}

// one wave per row, float4 per lane
__global__ __launch_bounds__(256) void l2norm_kernel(const float* __restrict__ in,
                                                     float* __restrict__ out, int N)
{
    int row = blockIdx.x * 4 + (threadIdx.x >> 6);
    if (row >= N) return;
    int d = (threadIdx.x & 63) * 4;
    float4 v = *reinterpret_cast<const float4*>(&in[(size_t)row * D_H + d]);
    float s = v.x * v.x + v.y * v.y + v.z * v.z + v.w * v.w;
    #pragma unroll
    for (int off = 32; off; off >>= 1) s += __shfl_xor(s, off);
    float inv = 1.f / fmaxf(sqrtf(s), 1e-12f);
    float4 o = make_float4(v.x * inv, v.y * inv, v.z * inv, v.w * inv);
    *reinterpret_cast<float4*>(&out[(size_t)row * D_H + d]) = o;
}

__global__ void fill_rows_kernel(float* __restrict__ p, float v, size_t n)
{
    size_t i = (size_t)blockIdx.x * 256 + threadIdx.x;
    if (i < n) p[i] = v;
}

__global__ void fill_kernel(float* __restrict__ p, float v, int n)
{
    int i = blockIdx.x * 256 + threadIdx.x;
    if (i < n) p[i] = v;
}

// tsum[j] += sum over 128-row chunk of r[i]*s0[i][j], float4 per thread
__global__ __launch_bounds__(256) void colsum_kernel(
    const float* __restrict__ s0, const float* __restrict__ r, float* __restrict__ tsum)
{
    int j4 = blockIdx.x * 256 + threadIdx.x;   // column group: cols j4*4 .. +3
    int i0 = blockIdx.y * 128;
    float4 s = make_float4(0.f, 0.f, 0.f, 0.f);
    for (int i = i0; i < i0 + 128; ++i) {
        float ri = r[i];
        const float4 v = *reinterpret_cast<const float4*>(&s0[(size_t)i * NT_N + j4 * 4]);
        s.x += ri * v.x; s.y += ri * v.y; s.z += ri * v.z; s.w += ri * v.w;
    }
    atomicAdd(&tsum[j4 * 4 + 0], s.x);
    atomicAdd(&tsum[j4 * 4 + 1], s.y);
    atomicAdd(&tsum[j4 * 4 + 2], s.z);
    atomicAdd(&tsum[j4 * 4 + 3], s.w);
}

__global__ void recip_kernel(const float* __restrict__ tsum, float* __restrict__ c)
{
    int j = blockIdx.x * 256 + threadIdx.x;
    if (j < NT_N) c[j] = 1.f / tsum[j];
}

// r[i] = 1 / sum_j s0[i][j]*c[j]
__global__ __launch_bounds__(256) void rowsum_kernel(
    const float* __restrict__ s0, const float* __restrict__ c, float* __restrict__ r)
{
    int i = blockIdx.x;
    int t = threadIdx.x;
    float s = 0.f;
    for (int j4 = t; j4 < NT_N / 4; j4 += 256) {
        const float4 v = *reinterpret_cast<const float4*>(&s0[(size_t)i * NT_N + j4 * 4]);
        const float4 cc = *reinterpret_cast<const float4*>(&c[j4 * 4]);
        s += v.x * cc.x + v.y * cc.y + v.z * cc.z + v.w * cc.w;
    }
    #pragma unroll
    for (int off = 32; off; off >>= 1) s += __shfl_xor(s, off);
    __shared__ float ws[4];
    if ((t & 63) == 0) ws[t >> 6] = s;
    __syncthreads();
    if (t == 0) r[i] = 1.f / (ws[0] + ws[1] + ws[2] + ws[3]);
}

// out[i][j] = r[i]*s0[i][j]*c[j], float4
__global__ void output_kernel(const float* __restrict__ s0, const float* __restrict__ r,
                              const float* __restrict__ c, float* __restrict__ out)
{
    size_t idx4 = (size_t)blockIdx.x * 256 + threadIdx.x;   // over NS*NT/4
    int i = (int)(idx4 >> 10);                              // 1024 float4 per row
    int j4 = (int)(idx4 & 1023);
    const float4 v = *reinterpret_cast<const float4*>(&s0[(size_t)i * NT_N + j4 * 4]);
    const float4 cc = *reinterpret_cast<const float4*>(&c[j4 * 4]);
    float ri = r[i];
    float4 o = make_float4(ri * v.x * cc.x, ri * v.y * cc.y, ri * v.z * cc.z, ri * v.w * cc.w);
    *reinterpret_cast<float4*>(&out[idx4 * 4]) = o;
}

extern "C" void kernel_launch(void* const* d_in, const int* in_sizes, int n_in,
                              void* d_out, int out_size, void* d_ws, size_t ws_size,
                              hipStream_t stream)
{
    const float* x_s = (const float*)d_in[0];
    const float* x_t = (const float*)d_in[1];
    const int* edges = (const int*)d_in[2];
    const int* edget = (const int*)d_in[3];
    const float* W1[3] = {(const float*)d_in[4], (const float*)d_in[8], (const float*)d_in[12]};
    const float* W2[3] = {(const float*)d_in[5], (const float*)d_in[9], (const float*)d_in[13]};
    const float* Wr[3] = {(const float*)d_in[6], (const float*)d_in[10], (const float*)d_in[14]};
    const float* br[3] = {(const float*)d_in[7], (const float*)d_in[11], (const float*)d_in[15]};
    const float* final_w = (const float*)d_in[16];
    const float* final_b = (const float*)d_in[17];
    float* out = (float*)d_out;

    const int* src_s = edges;
    const int* dst_s = edges + ES_E;
    const int* src_t = edget;
    const int* dst_t = edget + ET_E;

    // ---- workspace layout (floats) ----
    float* W = (float*)d_ws;
    size_t off = 0;
    float* S0   = W + off; off += (size_t)NT_N * NT_N;        // 16.78M
    float* CAT  = W + off; off += (size_t)NTOT * CAT_D;       // 7.25M
    float* TMP  = W + off; off += (size_t)NTOT * TMP_D;       // 6.22M (reused for HFIN/HN)
    float* WCAT = W + off; off += (size_t)(D_IN + 2 * D_H) * TMP_D; // 0.49M
    float* RVEC = W + off; off += NT_N;
    float* CVEC = W + off; off += NT_N;
    float* TSUM = W + off; off += NT_N;
    int* CNT_IN  = (int*)(W + off); off += NTOT;
    int* CNT_OUT = (int*)(W + off); off += NTOT;
    int* RP_IN   = (int*)(W + off); off += NTOT + 1;
    int* RP_OUT  = (int*)(W + off); off += NTOT + 1;
    int* CUR_IN  = (int*)(W + off); off += NTOT;
    int* CUR_OUT = (int*)(W + off); off += NTOT;
    int* CI_IN   = (int*)(W + off); off += ETOT;
    int* CI_OUT  = (int*)(W + off); off += ETOT;
    float* HFIN = TMP;                       // [NTOT][256]
    float* HN   = TMP + (size_t)NTOT * D_H;  // [NTOT][256]

    const int fan[3] = {D_IN, D_H, D_H};
    const int cat_off[4] = {0, 128, 384, 640};
    float* WC[3] = {WCAT, WCAT + (size_t)D_IN * TMP_D, WCAT + (size_t)(D_IN + D_H) * TMP_D};

    // ---- weight concat (once) ----
    for (int l = 0; l < 3; ++l)
        wcat_kernel<<<(fan[l] * TMP_D + 255) / 256, 256, 0, stream>>>(W1[l], W2[l], Wr[l], WC[l], fan[l]);

    // ---- CSR build (once, combined graph) ----
    hipMemsetAsync(CNT_IN, 0, NTOT * sizeof(int), stream);
    hipMemsetAsync(CNT_OUT, 0, NTOT * sizeof(int), stream);
    count_kernel<<<(ES_E + 255) / 256, 256, 0, stream>>>(dst_s, 0, CNT_IN, ES_E);
    count_kernel<<<(ET_E + 255) / 256, 256, 0, stream>>>(dst_t, NS_N, CNT_IN, ET_E);
    count_kernel<<<(ES_E + 255) / 256, 256, 0, stream>>>(src_s, 0, CNT_OUT, ES_E);
    count_kernel<<<(ET_E + 255) / 256, 256, 0, stream>>>(src_t, NS_N, CNT_OUT, ET_E);
    scan_kernel<<<1, 256, 0, stream>>>(CNT_IN, RP_IN, NTOT);
    scan_kernel<<<1, 256, 0, stream>>>(CNT_OUT, RP_OUT, NTOT);
    hipMemcpyAsync(CUR_IN, RP_IN, NTOT * sizeof(int), hipMemcpyDeviceToDevice, stream);
    hipMemcpyAsync(CUR_OUT, RP_OUT, NTOT * sizeof(int), hipMemcpyDeviceToDevice, stream);
    fill_csr_kernel<<<(ES_E + 255) / 256, 256, 0, stream>>>(dst_s, src_s, 0, CUR_IN, CI_IN, ES_E);
    fill_csr_kernel<<<(ET_E + 255) / 256, 256, 0, stream>>>(dst_t, src_t, NS_N, CUR_IN, CI_IN, ET_E);
    fill_csr_kernel<<<(ES_E + 255) / 256, 256, 0, stream>>>(src_s, dst_s, 0, CUR_OUT, CI_OUT, ES_E);
    fill_csr_kernel<<<(ET_E + 255) / 256, 256, 0, stream>>>(src_t, dst_t, NS_N, CUR_OUT, CI_OUT, ET_E);

    // ---- input copy ----
    copy_x_kernel<<<NTOT, 128, 0, stream>>>(x_s, x_t, CAT);

    // ---- 3 GNN layers on combined node set ----
    for (int l = 0; l < 3; ++l) {
        dim3 gg((NTOT + 63) / 64, TMP_D / 128);
        sgemm_kernel<64, 128, false, false, false><<<gg, 256, 0, stream>>>(
            CAT + cat_off[l], WC[l], nullptr, TMP, NTOT, TMP_D, fan[l], CAT_D, TMP_D, TMP_D);
        gather_combine_kernel<<<(NTOT + 3) / 4, 256, 0, stream>>>(
            TMP, RP_IN, CI_IN, RP_OUT, CI_OUT, br[l], CAT, cat_off[l + 1]);
    }

    // ---- final linear + l2norm ----
    {
        dim3 gf((NTOT + 63) / 64, D_H / 128);
        sgemm_kernel<64, 128, false, true, false><<<gf, 256, 0, stream>>>(
            CAT, final_w, final_b, HFIN, NTOT, D_H, CAT_D, CAT_D, D_H, D_H);
        l2norm_kernel<<<(NTOT + 3) / 4, 256, 0, stream>>>(HFIN, HN, NTOT);
    }

    // ---- match matrix: s0 = exp(ALPHA*(HNS @ HNT^T + EPS)) ----
    {
        dim3 gm((NS_N + 127) / 128, NT_N / 128);
        sgemm_kernel<128, 128, true, false, true><<<gm, 256, 0, stream>>>(
            HN, HN + (size_t)NS_N * D_H, nullptr, S0, NS_N, NT_N, D_H, D_H, D_H, NT_N);
        size_t dn = (size_t)(NT_N - NS_N) * NT_N;
        float dummy = expf(ALPHA_F * (EPS_F + EPS_F));
        fill_rows_kernel<<<(int)((dn + 255) / 256), 256, 0, stream>>>(
            S0 + (size_t)NS_N * NT_N, dummy, dn);
    }

    // ---- Sinkhorn: factorized r/c iterations ----
    fill_kernel<<<NT_N / 256, 256, 0, stream>>>(RVEC, 1.f, NT_N);
    fill_kernel<<<NT_N / 256, 256, 0, stream>>>(CVEC, 1.f, NT_N);
    for (int it = 0; it < 10; ++it) {
        if ((it % 2) == 0) {
            hipMemsetAsync(TSUM, 0, NT_N * sizeof(float), stream);
            dim3 gc(NT_N / 1024, NT_N / 128);
            colsum_kernel<<<gc, 256, 0, stream>>>(S0, RVEC, TSUM);
            recip_kernel<<<NT_N / 256, 256, 0, stream>>>(TSUM, CVEC);
        } else {
            rowsum_kernel<<<NT_N, 256, 0, stream>>>(S0, CVEC, RVEC);
        }
    }

    // ---- output ----
    size_t total4 = (size_t)NS_N * NT_N / 4;
    output_kernel<<<(int)((total4 + 255) / 256), 256, 0, stream>>>(S0, RVEC, CVEC, out);
}

// Round 3
// 767.614 us; speedup vs baseline: 2.6369x; 1.2959x over previous
//
#include <hip/hip_runtime.h>
#include <hip/hip_bf16.h>

#define NS_N 4000
#define NT_N 4096
#define NTOT 8096
#define ES_E 64000
#define ET_E 65536
#define ETOT 129536
#define D_IN 128
#define D_H 256
#define CAT_D 896               // 128 + 3*256
#define TMP_D 768               // 3*256 fused layer GEMM output
#define NDUM (NT_N - NS_N)      // 96 dummy sinkhorn rows
#define ALPHA_F 20.0f
#define EPS_F 1e-10f

typedef __attribute__((ext_vector_type(8))) short bf16x8;
typedef __attribute__((ext_vector_type(4))) float f32x4;

__device__ inline short f2bf(float v) {
    __hip_bfloat16 b = __float2bfloat16(v);   // RNE
    return *reinterpret_cast<short*>(&b);
}
__device__ inline float bf2f(short s) {
    __hip_bfloat16 b = *reinterpret_cast<__hip_bfloat16*>(&s);
    return __bfloat162float(b);
}
__device__ inline void splitf(float v, short& hi, short& lo) {
    hi = f2bf(v);
    lo = f2bf(v - bf2f(hi));
}

// ---------------------------------------------------------------------------
// Split-bf16 MFMA GEMM: C[M,N]fp32 = (Ahi+Alo)[M,K] @ (Bhi+Blo)^T[N,K]
// (B given transposed: BT[N][ldb]). 3-term split: hi*hi + hi*lo + lo*hi.
// 256 thr = 4 waves (2x2), wave tile 64x64, block 128x128, K-step 32.
// EPI: 0=none, 1=+bias, 2=exp(ALPHA*(v+EPS))
// ---------------------------------------------------------------------------
template<int EPI>
__global__ __launch_bounds__(256) void mfma_gemm_kernel(
    const short* __restrict__ Ahi, const short* __restrict__ Alo,
    const short* __restrict__ Bhi, const short* __restrict__ Blo,
    const float* __restrict__ bias, float* __restrict__ C,
    int M, int N, int K, int lda, int ldb, int ldc)
{
    __shared__ short sA[2][128][40];   // 40-pad: 80B row stride, 2-way bank = free
    __shared__ short sB[2][128][40];
    const int bm = blockIdx.x * 128;
    const int bn = blockIdx.y * 128;
    const int t = threadIdx.x;
    const int lane = t & 63, wv = t >> 6;
    const int wr = wv >> 1, wc = wv & 1;
    const int lr = lane & 15, lg = lane >> 4;
    const int srow = t >> 2, sseg = (t & 3) * 8;

    f32x4 acc[4][4];
    #pragma unroll
    for (int i = 0; i < 4; ++i)
        #pragma unroll
        for (int j = 0; j < 4; ++j) {
            f32x4 z = {0.f, 0.f, 0.f, 0.f};
            acc[i][j] = z;
        }

    for (int k0 = 0; k0 < K; k0 += 32) {
        #pragma unroll
        for (int h = 0; h < 2; ++h) {
            int row = srow + h * 64;
            int ge = k0 + sseg;
            int gm = bm + row;
            int4 vh = make_int4(0, 0, 0, 0), vl = make_int4(0, 0, 0, 0);
            if (gm < M) {
                vh = *reinterpret_cast<const int4*>(&Ahi[(size_t)gm * lda + ge]);
                vl = *reinterpret_cast<const int4*>(&Alo[(size_t)gm * lda + ge]);
            }
            *reinterpret_cast<int4*>(&sA[0][row][sseg]) = vh;
            *reinterpret_cast<int4*>(&sA[1][row][sseg]) = vl;
            int gn = bn + row;   // N always multiple of 128 here
            *reinterpret_cast<int4*>(&sB[0][row][sseg]) =
                *reinterpret_cast<const int4*>(&Bhi[(size_t)gn * ldb + ge]);
            *reinterpret_cast<int4*>(&sB[1][row][sseg]) =
                *reinterpret_cast<const int4*>(&Blo[(size_t)gn * ldb + ge]);
        }
        __syncthreads();
        bf16x8 ah[4], al[4], bh[4], bl[4];
        #pragma unroll
        for (int i = 0; i < 4; ++i) {
            ah[i] = *reinterpret_cast<const bf16x8*>(&sA[0][wr * 64 + i * 16 + lr][lg * 8]);
            al[i] = *reinterpret_cast<const bf16x8*>(&sA[1][wr * 64 + i * 16 + lr][lg * 8]);
            bh[i] = *reinterpret_cast<const bf16x8*>(&sB[0][wc * 64 + i * 16 + lr][lg * 8]);
            bl[i] = *reinterpret_cast<const bf16x8*>(&sB[1][wc * 64 + i * 16 + lr][lg * 8]);
        }
        #pragma unroll
        for (int i = 0; i < 4; ++i)
            #pragma unroll
            for (int j = 0; j < 4; ++j) {
                acc[i][j] = __builtin_amdgcn_mfma_f32_16x16x32_bf16(ah[i], bh[j], acc[i][j], 0, 0, 0);
                acc[i][j] = __builtin_amdgcn_mfma_f32_16x16x32_bf16(ah[i], bl[j], acc[i][j], 0, 0, 0);
                acc[i][j] = __builtin_amdgcn_mfma_f32_16x16x32_bf16(al[i], bh[j], acc[i][j], 0, 0, 0);
            }
        __syncthreads();
    }
    // epilogue: C/D layout col=lane&15, row=(lane>>4)*4+reg [m89-verified]
    #pragma unroll
    for (int i = 0; i < 4; ++i) {
        #pragma unroll
        for (int j = 0; j < 4; ++j) {
            int col = bn + wc * 64 + j * 16 + lr;
            #pragma unroll
            for (int r = 0; r < 4; ++r) {
                int row = bm + wr * 64 + i * 16 + lg * 4 + r;
                if (row < M) {
                    float v = acc[i][j][r];
                    if (EPI == 1) v += bias[col];
                    if (EPI == 2) v = expf(ALPHA_F * (v + EPS_F));
                    C[(size_t)row * ldc + col] = v;
                }
            }
        }
    }
}

// ---------------------------------------------------------------------------
// weight transpose+split: W[K][Nw] fp32 -> WT_hi/lo[(roff+n)*ldt + k] bf16
// ---------------------------------------------------------------------------
__global__ void wsplitT_kernel(const float* __restrict__ W, short* __restrict__ WThi,
                               short* __restrict__ WTlo, int K, int Nw, int roff, int ldt)
{
    int idx = blockIdx.x * 256 + threadIdx.x;
    if (idx < K * Nw) {
        int k = idx / Nw, n = idx % Nw;
        short hi, lo;
        splitf(W[idx], hi, lo);
        WThi[(size_t)(roff + n) * ldt + k] = hi;
        WTlo[(size_t)(roff + n) * ldt + k] = lo;
    }
}

// ---------------------------------------------------------------------------
// CSR build
// ---------------------------------------------------------------------------
__global__ void count_kernel(const int* __restrict__ idx, int off, int* __restrict__ cnt, int E)
{
    int e = blockIdx.x * 256 + threadIdx.x;
    if (e < E) atomicAdd(&cnt[idx[e] + off], 1);
}

__global__ __launch_bounds__(256) void scan_kernel(const int* __restrict__ cnt,
                                                   int* __restrict__ rowptr, int n)
{
    __shared__ int sums[256];
    const int t = threadIdx.x;
    const int per = (n + 255) / 256;
    const int lo = t * per, hi = min((t + 1) * per, n);
    int s = 0;
    for (int i = lo; i < hi; ++i) s += cnt[i];
    sums[t] = s;
    __syncthreads();
    for (int off = 1; off < 256; off <<= 1) {
        int v = (t >= off) ? sums[t - off] : 0;
        __syncthreads();
        sums[t] += v;
        __syncthreads();
    }
    int base = (t == 0) ? 0 : sums[t - 1];
    for (int i = lo; i < hi; ++i) { rowptr[i] = base; base += cnt[i]; }
    if (t == 255) rowptr[n] = base;
}

__global__ void fill_csr_kernel(const int* __restrict__ key, const int* __restrict__ val,
                                int off, int* __restrict__ cur, int* __restrict__ col, int E)
{
    int e = blockIdx.x * 256 + threadIdx.x;
    if (e < E) {
        int pos = atomicAdd(&cur[key[e] + off], 1);
        col[pos] = val[e] + off;
    }
}

// cat[i, 0:128] = x[i, :] (split bf16)
__global__ void copy_x_kernel(const float* __restrict__ xs, const float* __restrict__ xt,
                              short* __restrict__ CAThi, short* __restrict__ CATlo)
{
    int i = blockIdx.x, d = threadIdx.x;  // 128 threads
    float v = (i < NS_N) ? xs[(size_t)i * D_IN + d] : xt[(size_t)(i - NS_N) * D_IN + d];
    short hi, lo;
    splitf(v, hi, lo);
    CAThi[(size_t)i * CAT_D + d] = hi;
    CATlo[(size_t)i * CAT_D + d] = lo;
}

// ---------------------------------------------------------------------------
// gather + mean + root + bias + relu -> split bf16 CAT slice
// one 64-lane wave per node, float4 per lane
// ---------------------------------------------------------------------------
__global__ __launch_bounds__(256) void gather_combine_kernel(
    const float* __restrict__ TMP,
    const int* __restrict__ rp_in, const int* __restrict__ ci_in,
    const int* __restrict__ rp_out, const int* __restrict__ ci_out,
    const float* __restrict__ br, short* __restrict__ CAThi, short* __restrict__ CATlo,
    int catoff)
{
    int node = blockIdx.x * 4 + (threadIdx.x >> 6);
    if (node >= NTOT) return;
    int d = (threadIdx.x & 63) * 4;

    float4 a1 = make_float4(0.f, 0.f, 0.f, 0.f);
    int b0 = rp_in[node], e0 = rp_in[node + 1];
    for (int e = b0; e < e0; ++e) {
        const float4 v = *reinterpret_cast<const float4*>(&TMP[(size_t)ci_in[e] * TMP_D + d]);
        a1.x += v.x; a1.y += v.y; a1.z += v.z; a1.w += v.w;
    }
    float s1 = 1.f / (float)max(e0 - b0, 1);

    float4 a2 = make_float4(0.f, 0.f, 0.f, 0.f);
    int b1 = rp_out[node], e1 = rp_out[node + 1];
    for (int e = b1; e < e1; ++e) {
        const float4 v = *reinterpret_cast<const float4*>(&TMP[(size_t)ci_out[e] * TMP_D + 256 + d]);
        a2.x += v.x; a2.y += v.y; a2.z += v.z; a2.w += v.w;
    }
    float s2 = 1.f / (float)max(e1 - b1, 1);

    const float4 rt = *reinterpret_cast<const float4*>(&TMP[(size_t)node * TMP_D + 512 + d]);
    const float4 bb = *reinterpret_cast<const float4*>(&br[d]);
    float o[4];
    o[0] = fmaxf(rt.x + bb.x + a1.x * s1 + a2.x * s2, 0.f);
    o[1] = fmaxf(rt.y + bb.y + a1.y * s1 + a2.y * s2, 0.f);
    o[2] = fmaxf(rt.z + bb.z + a1.z * s1 + a2.z * s2, 0.f);
    o[3] = fmaxf(rt.w + bb.w + a1.w * s1 + a2.w * s2, 0.f);
    short h[4], l[4];
    #pragma unroll
    for (int q = 0; q < 4; ++q) splitf(o[q], h[q], l[q]);
    *reinterpret_cast<short4*>(&CAThi[(size_t)node * CAT_D + catoff + d]) = make_short4(h[0], h[1], h[2], h[3]);
    *reinterpret_cast<short4*>(&CATlo[(size_t)node * CAT_D + catoff + d]) = make_short4(l[0], l[1], l[2], l[3]);
}

// row L2 normalization -> split bf16; one wave per row
__global__ __launch_bounds__(256) void l2norm_kernel(const float* __restrict__ in,
                                                     short* __restrict__ outhi,
                                                     short* __restrict__ outlo, int N)
{
    int row = blockIdx.x * 4 + (threadIdx.x >> 6);
    if (row >= N) return;
    int d = (threadIdx.x & 63) * 4;
    float4 v = *reinterpret_cast<const float4*>(&in[(size_t)row * D_H + d]);
    float s = v.x * v.x + v.y * v.y + v.z * v.z + v.w * v.w;
    #pragma unroll
    for (int off = 32; off; off >>= 1) s += __shfl_xor(s, off);
    float inv = 1.f / fmaxf(sqrtf(s), 1e-12f);
    float o[4] = {v.x * inv, v.y * inv, v.z * inv, v.w * inv};
    short h[4], l[4];
    #pragma unroll
    for (int q = 0; q < 4; ++q) splitf(o[q], h[q], l[q]);
    *reinterpret_cast<short4*>(&outhi[(size_t)row * D_H + d]) = make_short4(h[0], h[1], h[2], h[3]);
    *reinterpret_cast<short4*>(&outlo[(size_t)row * D_H + d]) = make_short4(l[0], l[1], l[2], l[3]);
}

__global__ void fill_kernel(float* __restrict__ p, float v, int n)
{
    int i = blockIdx.x * 256 + threadIdx.x;
    if (i < n) p[i] = v;
}

// tsum[j] += sum over real-row chunk of r[i]*s0[i][j], float4 per thread
__global__ __launch_bounds__(256) void colsum_kernel(
    const float* __restrict__ s0, const float* __restrict__ r, float* __restrict__ tsum)
{
    int j4 = blockIdx.x * 256 + threadIdx.x;   // cols j4*4 .. +3
    int i0 = blockIdx.y * 128;
    int iend = min(i0 + 128, NS_N);
    float4 s = make_float4(0.f, 0.f, 0.f, 0.f);
    for (int i = i0; i < iend; ++i) {
        float ri = r[i];
        const float4 v = *reinterpret_cast<const float4*>(&s0[(size_t)i * NT_N + j4 * 4]);
        s.x += ri * v.x; s.y += ri * v.y; s.z += ri * v.z; s.w += ri * v.w;
    }
    atomicAdd(&tsum[j4 * 4 + 0], s.x);
    atomicAdd(&tsum[j4 * 4 + 1], s.y);
    atomicAdd(&tsum[j4 * 4 + 2], s.z);
    atomicAdd(&tsum[j4 * 4 + 3], s.w);
}

// c[j] = 1/(tsum[j] + NDUM * dummyv * rd)   (dummy rows folded analytically)
__global__ void recip_kernel(const float* __restrict__ tsum, const float* __restrict__ rd,
                             float* __restrict__ c, float dummyv)
{
    int j = blockIdx.x * 256 + threadIdx.x;
    if (j < NT_N) c[j] = 1.f / (tsum[j] + (float)NDUM * dummyv * rd[0]);
}

// real rows: r[i] = 1/sum_j s0[i][j]*c[j];  block NS_N: rd = 1/(dummyv*sum_j c[j])
__global__ __launch_bounds__(256) void rowsum_kernel(
    const float* __restrict__ s0, const float* __restrict__ c,
    float* __restrict__ r, float* __restrict__ rd, float dummyv)
{
    int i = blockIdx.x;
    int t = threadIdx.x;
    float s = 0.f;
    if (i < NS_N) {
        for (int j4 = t; j4 < NT_N / 4; j4 += 256) {
            const float4 v = *reinterpret_cast<const float4*>(&s0[(size_t)i * NT_N + j4 * 4]);
            const float4 cc = *reinterpret_cast<const float4*>(&c[j4 * 4]);
            s += v.x * cc.x + v.y * cc.y + v.z * cc.z + v.w * cc.w;
        }
    } else {
        for (int j = t; j < NT_N; j += 256) s += c[j];
    }
    #pragma unroll
    for (int off = 32; off; off >>= 1) s += __shfl_xor(s, off);
    __shared__ float ws[4];
    if ((t & 63) == 0) ws[t >> 6] = s;
    __syncthreads();
    if (t == 0) {
        float tot = ws[0] + ws[1] + ws[2] + ws[3];
        if (i < NS_N) r[i] = 1.f / tot;
        else rd[0] = 1.f / (dummyv * tot);
    }
}

// out[i][j] = r[i]*s0[i][j]*c[j], float4
__global__ void output_kernel(const float* __restrict__ s0, const float* __restrict__ r,
                              const float* __restrict__ c, float* __restrict__ out)
{
    size_t idx4 = (size_t)blockIdx.x * 256 + threadIdx.x;   // over NS*NT/4
    int i = (int)(idx4 >> 10);                              // 1024 float4 per row
    int j4 = (int)(idx4 & 1023);
    const float4 v = *reinterpret_cast<const float4*>(&s0[(size_t)i * NT_N + j4 * 4]);
    const float4 cc = *reinterpret_cast<const float4*>(&c[j4 * 4]);
    float ri = r[i];
    float4 o = make_float4(ri * v.x * cc.x, ri * v.y * cc.y, ri * v.z * cc.z, ri * v.w * cc.w);
    *reinterpret_cast<float4*>(&out[idx4 * 4]) = o;
}

extern "C" void kernel_launch(void* const* d_in, const int* in_sizes, int n_in,
                              void* d_out, int out_size, void* d_ws, size_t ws_size,
                              hipStream_t stream)
{
    const float* x_s = (const float*)d_in[0];
    const float* x_t = (const float*)d_in[1];
    const int* edges = (const int*)d_in[2];
    const int* edget = (const int*)d_in[3];
    const float* W1[3] = {(const float*)d_in[4], (const float*)d_in[8], (const float*)d_in[12]};
    const float* W2[3] = {(const float*)d_in[5], (const float*)d_in[9], (const float*)d_in[13]};
    const float* Wr[3] = {(const float*)d_in[6], (const float*)d_in[10], (const float*)d_in[14]};
    const float* br[3] = {(const float*)d_in[7], (const float*)d_in[11], (const float*)d_in[15]};
    const float* final_w = (const float*)d_in[16];
    const float* final_b = (const float*)d_in[17];
    float* out = (float*)d_out;

    const int* src_s = edges;
    const int* dst_s = edges + ES_E;
    const int* src_t = edget;
    const int* dst_t = edget + ET_E;

    // ---- workspace layout (float units) ----
    float* W = (float*)d_ws;
    size_t off = 0;
    float* S0 = W + off;  off += (size_t)NS_N * NT_N;                 // 16.38M
    float* TMP = W + off; off += (size_t)NTOT * TMP_D;                // 6.22M (also HFIN+HN)
    short* CAThi = (short*)(W + off); off += (size_t)NTOT * CAT_D / 2;  // 3.63M
    short* CATlo = (short*)(W + off); off += (size_t)NTOT * CAT_D / 2;
    // per-layer weight slabs [768][K] hi/lo
    const int fan[3] = {D_IN, D_H, D_H};
    short* WThi[3]; short* WTlo[3];
    for (int l = 0; l < 3; ++l) {
        WThi[l] = (short*)(W + off); off += (size_t)TMP_D * fan[l] / 2;
        WTlo[l] = (short*)(W + off); off += (size_t)TMP_D * fan[l] / 2;
    }
    short* WFhi = (short*)(W + off); off += (size_t)D_H * CAT_D / 2;
    short* WFlo = (short*)(W + off); off += (size_t)D_H * CAT_D / 2;
    float* RVEC = W + off; off += NS_N;
    float* CVEC = W + off; off += NT_N;
    float* TSUM = W + off; off += NT_N;
    float* RD   = W + off; off += 4;
    int* CNT_IN  = (int*)(W + off); off += NTOT;
    int* CNT_OUT = (int*)(W + off); off += NTOT;
    int* RP_IN   = (int*)(W + off); off += NTOT + 1;
    int* RP_OUT  = (int*)(W + off); off += NTOT + 3;
    int* CUR_IN  = (int*)(W + off); off += NTOT;
    int* CUR_OUT = (int*)(W + off); off += NTOT;
    int* CI_IN   = (int*)(W + off); off += ETOT;
    int* CI_OUT  = (int*)(W + off); off += ETOT;
    // HFIN (fp32) and HN hi/lo (bf16) overlaid inside TMP (final GEMM doesn't read TMP)
    float* HFIN = TMP;                                        // [NTOT][256] f32
    short* HNhi = (short*)(TMP + (size_t)NTOT * D_H);         // [NTOT][256] bf16
    short* HNlo = (short*)(TMP + (size_t)NTOT * D_H + (size_t)NTOT * D_H / 2);

    const int cat_off[4] = {0, 128, 384, 640};

    // ---- weight transpose+split (every launch; cheap) ----
    for (int l = 0; l < 3; ++l) {
        int K = fan[l];
        int n = K * D_H;
        wsplitT_kernel<<<(n + 255) / 256, 256, 0, stream>>>(W1[l], WThi[l], WTlo[l], K, D_H, 0, K);
        wsplitT_kernel<<<(n + 255) / 256, 256, 0, stream>>>(W2[l], WThi[l], WTlo[l], K, D_H, 256, K);
        wsplitT_kernel<<<(n + 255) / 256, 256, 0, stream>>>(Wr[l], WThi[l], WTlo[l], K, D_H, 512, K);
    }
    wsplitT_kernel<<<(CAT_D * D_H + 255) / 256, 256, 0, stream>>>(final_w, WFhi, WFlo, CAT_D, D_H, 0, CAT_D);

    // ---- CSR build (combined graph) ----
    hipMemsetAsync(CNT_IN, 0, NTOT * sizeof(int), stream);
    hipMemsetAsync(CNT_OUT, 0, NTOT * sizeof(int), stream);
    count_kernel<<<(ES_E + 255) / 256, 256, 0, stream>>>(dst_s, 0, CNT_IN, ES_E);
    count_kernel<<<(ET_E + 255) / 256, 256, 0, stream>>>(dst_t, NS_N, CNT_IN, ET_E);
    count_kernel<<<(ES_E + 255) / 256, 256, 0, stream>>>(src_s, 0, CNT_OUT, ES_E);
    count_kernel<<<(ET_E + 255) / 256, 256, 0, stream>>>(src_t, NS_N, CNT_OUT, ET_E);
    scan_kernel<<<1, 256, 0, stream>>>(CNT_IN, RP_IN, NTOT);
    scan_kernel<<<1, 256, 0, stream>>>(CNT_OUT, RP_OUT, NTOT);
    hipMemcpyAsync(CUR_IN, RP_IN, NTOT * sizeof(int), hipMemcpyDeviceToDevice, stream);
    hipMemcpyAsync(CUR_OUT, RP_OUT, NTOT * sizeof(int), hipMemcpyDeviceToDevice, stream);
    fill_csr_kernel<<<(ES_E + 255) / 256, 256, 0, stream>>>(dst_s, src_s, 0, CUR_IN, CI_IN, ES_E);
    fill_csr_kernel<<<(ET_E + 255) / 256, 256, 0, stream>>>(dst_t, src_t, NS_N, CUR_IN, CI_IN, ET_E);
    fill_csr_kernel<<<(ES_E + 255) / 256, 256, 0, stream>>>(src_s, dst_s, 0, CUR_OUT, CI_OUT, ES_E);
    fill_csr_kernel<<<(ET_E + 255) / 256, 256, 0, stream>>>(src_t, dst_t, NS_N, CUR_OUT, CI_OUT, ET_E);

    // ---- input copy (split) ----
    copy_x_kernel<<<NTOT, 128, 0, stream>>>(x_s, x_t, CAThi, CATlo);

    // ---- 3 GNN layers ----
    for (int l = 0; l < 3; ++l) {
        dim3 gg((NTOT + 127) / 128, TMP_D / 128);
        mfma_gemm_kernel<0><<<gg, 256, 0, stream>>>(
            CAThi + cat_off[l], CATlo + cat_off[l], WThi[l], WTlo[l], nullptr, TMP,
            NTOT, TMP_D, fan[l], CAT_D, fan[l], TMP_D);
        gather_combine_kernel<<<(NTOT + 3) / 4, 256, 0, stream>>>(
            TMP, RP_IN, CI_IN, RP_OUT, CI_OUT, br[l], CAThi, CATlo, cat_off[l + 1]);
    }

    // ---- final linear + l2norm ----
    {
        dim3 gf((NTOT + 127) / 128, D_H / 128);
        mfma_gemm_kernel<1><<<gf, 256, 0, stream>>>(
            CAThi, CATlo, WFhi, WFlo, final_b, HFIN, NTOT, D_H, CAT_D, CAT_D, CAT_D, D_H);
        l2norm_kernel<<<(NTOT + 3) / 4, 256, 0, stream>>>(HFIN, HNhi, HNlo, NTOT);
    }

    // ---- match matrix: s0 = exp(ALPHA*(HNS @ HNT^T + EPS)), real rows only ----
    {
        dim3 gm((NS_N + 127) / 128, NT_N / 128);
        mfma_gemm_kernel<2><<<gm, 256, 0, stream>>>(
            HNhi, HNlo, HNhi + (size_t)NS_N * D_H, HNlo + (size_t)NS_N * D_H, nullptr, S0,
            NS_N, NT_N, D_H, D_H, D_H, NT_N);
    }

    // ---- Sinkhorn: factorized r/c + analytic dummy-row scalar rd ----
    const float dummyv = expf(ALPHA_F * (EPS_F + EPS_F));
    fill_kernel<<<(NS_N + 255) / 256, 256, 0, stream>>>(RVEC, 1.f, NS_N);
    fill_kernel<<<NT_N / 256, 256, 0, stream>>>(CVEC, 1.f, NT_N);
    fill_kernel<<<1, 256, 0, stream>>>(RD, 1.f, 1);
    for (int it = 0; it < 10; ++it) {
        if ((it % 2) == 0) {
            hipMemsetAsync(TSUM, 0, NT_N * sizeof(float), stream);
            dim3 gc(NT_N / 1024, (NS_N + 127) / 128);
            colsum_kernel<<<gc, 256, 0, stream>>>(S0, RVEC, TSUM);
            recip_kernel<<<NT_N / 256, 256, 0, stream>>>(TSUM, RD, CVEC, dummyv);
        } else {
            rowsum_kernel<<<NS_N + 1, 256, 0, stream>>>(S0, CVEC, RVEC, RD, dummyv);
        }
    }

    // ---- output ----
    size_t total4 = (size_t)NS_N * NT_N / 4;
    output_kernel<<<(int)((total4 + 255) / 256), 256, 0, stream>>>(S0, RVEC, CVEC, out);
}

// Round 4
// 627.258 us; speedup vs baseline: 3.2269x; 1.2238x over previous
//
#include <hip/hip_runtime.h>
#include <hip/hip_bf16.h>

#define NS_N 4000
#define NT_N 4096
#define NTOT 8096
#define ES_E 64000
#define ET_E 65536
#define ETOT 129536
#define D_IN 128
#define D_H 256
#define CAT_D 896               // 128 + 3*256
#define TMP_D 768               // 3*256 fused layer GEMM output
#define NDUM (NT_N - NS_N)      // 96 dummy sinkhorn rows
#define ALPHA_F 20.0f
#define EPS_F 1e-10f

typedef __attribute__((ext_vector_type(8))) short bf16x8;
typedef __attribute__((ext_vector_type(4))) float f32x4;

__device__ inline short f2bf(float v) {
    __hip_bfloat16 b = __float2bfloat16(v);   // RNE
    return *reinterpret_cast<short*>(&b);
}
__device__ inline float bf2f(short s) {
    __hip_bfloat16 b = *reinterpret_cast<__hip_bfloat16*>(&s);
    return __bfloat162float(b);
}
__device__ inline void splitf(float v, short& hi, short& lo) {
    hi = f2bf(v);
    lo = f2bf(v - bf2f(hi));
}

typedef __attribute__((address_space(1))) const char gas_t;
typedef __attribute__((address_space(3))) char las_t;
__device__ inline void gload16(const short* g, short* l) {
    __builtin_amdgcn_global_load_lds((gas_t*)g, (las_t*)l, 16, 0, 0);
}

// ---------------------------------------------------------------------------
// Split-bf16 MFMA GEMM v2: C[M,N]f32 = (Ahi+Alo)[M,K] @ (Bhi+Blo)^T[N,K]
// global_load_lds staging (width 16, linear LDS [128][32] per half).
// 256 thr = 4 waves (2x2), wave tile 64x64, block 128x128, K-step 32.
// EPI: 0=none, 1=+bias, 2=exp(ALPHA*(v+EPS))
// A rows clamped to M-1 (garbage rows never stored); N,K must be mult of 32.
// ---------------------------------------------------------------------------
template<int EPI>
__global__ __launch_bounds__(256) void mfma_gemm_kernel(
    const short* __restrict__ Ahi, const short* __restrict__ Alo,
    const short* __restrict__ Bhi, const short* __restrict__ Blo,
    const float* __restrict__ bias, float* __restrict__ C,
    int M, int N, int K, int lda, int ldb, int ldc)
{
    __shared__ short sAh[128 * 32];   // 8 KB each, linear: row*32 + seg
    __shared__ short sAl[128 * 32];
    __shared__ short sBh[128 * 32];
    __shared__ short sBl[128 * 32];
    const int bm = blockIdx.x * 128;
    const int bn = blockIdx.y * 128;
    const int t = threadIdx.x;
    const int lane = t & 63, wv = t >> 6;
    const int wr = wv >> 1, wc = wv & 1;
    const int lr = lane & 15, lg = lane >> 4;

    f32x4 acc[4][4];
    #pragma unroll
    for (int i = 0; i < 4; ++i)
        #pragma unroll
        for (int j = 0; j < 4; ++j) {
            f32x4 z = {0.f, 0.f, 0.f, 0.f};
            acc[i][j] = z;
        }

    // per-lane staging geometry: chunk q covers rows 16q..16q+15;
    // lane i -> row_local = i>>2, seg = i&3 (16B) == linear lane*16B in LDS.
    const int srow = lane >> 2, sseg = (lane & 3) * 8;

    for (int k0 = 0; k0 < K; k0 += 32) {
        auto stage = [&](const short* src, short* dst, int rowbase, int ld, int maxrow) {
            #pragma unroll
            for (int q = 0; q < 8; ++q) {
                int gr = min(rowbase + q * 16 + srow, maxrow);
                gload16(src + (size_t)gr * ld + k0 + sseg, dst + q * 512);
            }
        };
        if (wv == 0)      stage(Ahi, sAh, bm, lda, M - 1);
        else if (wv == 1) stage(Alo, sAl, bm, lda, M - 1);
        else if (wv == 2) stage(Bhi, sBh, bn, ldb, N - 1);
        else              stage(Blo, sBl, bn, ldb, N - 1);
        __syncthreads();

        bf16x8 ah[4], al[4], bh[4], bl[4];
        #pragma unroll
        for (int i = 0; i < 4; ++i) {
            int oa = (wr * 64 + i * 16 + lr) * 32 + lg * 8;
            ah[i] = *reinterpret_cast<const bf16x8*>(&sAh[oa]);
            al[i] = *reinterpret_cast<const bf16x8*>(&sAl[oa]);
            int ob = (wc * 64 + i * 16 + lr) * 32 + lg * 8;
            bh[i] = *reinterpret_cast<const bf16x8*>(&sBh[ob]);
            bl[i] = *reinterpret_cast<const bf16x8*>(&sBl[ob]);
        }
        #pragma unroll
        for (int i = 0; i < 4; ++i)
            #pragma unroll
            for (int j = 0; j < 4; ++j) {
                acc[i][j] = __builtin_amdgcn_mfma_f32_16x16x32_bf16(ah[i], bh[j], acc[i][j], 0, 0, 0);
                acc[i][j] = __builtin_amdgcn_mfma_f32_16x16x32_bf16(ah[i], bl[j], acc[i][j], 0, 0, 0);
                acc[i][j] = __builtin_amdgcn_mfma_f32_16x16x32_bf16(al[i], bh[j], acc[i][j], 0, 0, 0);
            }
        __syncthreads();
    }
    // epilogue: C/D layout col=lane&15, row=(lane>>4)*4+reg [m89-verified]
    #pragma unroll
    for (int i = 0; i < 4; ++i) {
        #pragma unroll
        for (int j = 0; j < 4; ++j) {
            int col = bn + wc * 64 + j * 16 + lr;
            #pragma unroll
            for (int r = 0; r < 4; ++r) {
                int row = bm + wr * 64 + i * 16 + lg * 4 + r;
                if (row < M) {
                    float v = acc[i][j][r];
                    if (EPI == 1) v += bias[col];
                    if (EPI == 2) v = expf(ALPHA_F * (v + EPS_F));
                    C[(size_t)row * ldc + col] = v;
                }
            }
        }
    }
}

// ---------------------------------------------------------------------------
// per-layer weight transpose+split: [W1|W2|Wr] (each [K][256]) -> WT[768][K] hi/lo
// ---------------------------------------------------------------------------
__global__ void wsplit3_kernel(const float* __restrict__ W1, const float* __restrict__ W2,
                               const float* __restrict__ Wr, short* __restrict__ WThi,
                               short* __restrict__ WTlo, int K)
{
    int idx = blockIdx.x * 256 + threadIdx.x;
    if (idx < K * TMP_D) {
        int k = idx / TMP_D, c = idx % TMP_D;
        float v = (c < 256) ? W1[k * 256 + c]
                : (c < 512) ? W2[k * 256 + (c - 256)]
                            : Wr[k * 256 + (c - 512)];
        short hi, lo;
        splitf(v, hi, lo);
        WThi[(size_t)c * K + k] = hi;
        WTlo[(size_t)c * K + k] = lo;
    }
}

__global__ void wsplitT_kernel(const float* __restrict__ W, short* __restrict__ WThi,
                               short* __restrict__ WTlo, int K, int Nw)
{
    int idx = blockIdx.x * 256 + threadIdx.x;
    if (idx < K * Nw) {
        int k = idx / Nw, n = idx % Nw;
        short hi, lo;
        splitf(W[idx], hi, lo);
        WThi[(size_t)n * K + k] = hi;
        WTlo[(size_t)n * K + k] = lo;
    }
}

// ---------------------------------------------------------------------------
// CSR build: dir 0 = in-edges (key dst), dir 1 = out-edges (key src)
// ---------------------------------------------------------------------------
__global__ void count2_kernel(const int* __restrict__ es, const int* __restrict__ et,
                              int* __restrict__ cin, int* __restrict__ cout)
{
    int e = blockIdx.x * 256 + threadIdx.x;
    int dir = blockIdx.y;
    int* cnt = dir ? cout : cin;
    if (e < ES_E) {
        int key = dir ? es[e] : es[e + ES_E];
        atomicAdd(&cnt[key], 1);
    } else if (e < ETOT) {
        int e2 = e - ES_E;
        int key = dir ? et[e2] : et[e2 + ET_E];
        atomicAdd(&cnt[key + NS_N], 1);
    }
}

__global__ __launch_bounds__(256) void scan2_kernel(const int* __restrict__ cin,
                                                    const int* __restrict__ cout,
                                                    int* __restrict__ rpin, int* __restrict__ rpout,
                                                    int* __restrict__ curin, int* __restrict__ curout)
{
    const int* cnt = blockIdx.x ? cout : cin;
    int* rowptr = blockIdx.x ? rpout : rpin;
    int* cur = blockIdx.x ? curout : curin;
    __shared__ int sums[256];
    const int t = threadIdx.x;
    const int per = (NTOT + 255) / 256;
    const int lo = t * per, hi = min((t + 1) * per, NTOT);
    int s = 0;
    for (int i = lo; i < hi; ++i) s += cnt[i];
    sums[t] = s;
    __syncthreads();
    for (int off = 1; off < 256; off <<= 1) {
        int v = (t >= off) ? sums[t - off] : 0;
        __syncthreads();
        sums[t] += v;
        __syncthreads();
    }
    int base = (t == 0) ? 0 : sums[t - 1];
    for (int i = lo; i < hi; ++i) { rowptr[i] = base; cur[i] = base; base += cnt[i]; }
    if (t == 255) rowptr[NTOT] = base;
}

__global__ void fill2_kernel(const int* __restrict__ es, const int* __restrict__ et,
                             int* __restrict__ curin, int* __restrict__ curout,
                             int* __restrict__ ciin, int* __restrict__ ciout)
{
    int e = blockIdx.x * 256 + threadIdx.x;
    int dir = blockIdx.y;
    int* cur = dir ? curout : curin;
    int* ci = dir ? ciout : ciin;
    int key, val, off;
    if (e < ES_E) {
        key = dir ? es[e] : es[e + ES_E];
        val = dir ? es[e + ES_E] : es[e];
        off = 0;
    } else if (e < ETOT) {
        int e2 = e - ES_E;
        key = dir ? et[e2] : et[e2 + ET_E];
        val = dir ? et[e2 + ET_E] : et[e2];
        off = NS_N;
    } else return;
    int pos = atomicAdd(&cur[key + off], 1);
    ci[pos] = val + off;
}

// cat[i, 0:128] = x[i, :] (split bf16)
__global__ void copy_x_kernel(const float* __restrict__ xs, const float* __restrict__ xt,
                              short* __restrict__ CAThi, short* __restrict__ CATlo)
{
    int i = blockIdx.x, d = threadIdx.x;  // 128 threads
    float v = (i < NS_N) ? xs[(size_t)i * D_IN + d] : xt[(size_t)(i - NS_N) * D_IN + d];
    short hi, lo;
    splitf(v, hi, lo);
    CAThi[(size_t)i * CAT_D + d] = hi;
    CATlo[(size_t)i * CAT_D + d] = lo;
}

// ---------------------------------------------------------------------------
// gather + mean + root + bias + relu -> split bf16 CAT slice
// ---------------------------------------------------------------------------
__global__ __launch_bounds__(256) void gather_combine_kernel(
    const float* __restrict__ TMP,
    const int* __restrict__ rp_in, const int* __restrict__ ci_in,
    const int* __restrict__ rp_out, const int* __restrict__ ci_out,
    const float* __restrict__ br, short* __restrict__ CAThi, short* __restrict__ CATlo,
    int catoff)
{
    int node = blockIdx.x * 4 + (threadIdx.x >> 6);
    if (node >= NTOT) return;
    int d = (threadIdx.x & 63) * 4;

    float4 a1 = make_float4(0.f, 0.f, 0.f, 0.f);
    int b0 = rp_in[node], e0 = rp_in[node + 1];
    for (int e = b0; e < e0; ++e) {
        const float4 v = *reinterpret_cast<const float4*>(&TMP[(size_t)ci_in[e] * TMP_D + d]);
        a1.x += v.x; a1.y += v.y; a1.z += v.z; a1.w += v.w;
    }
    float s1 = 1.f / (float)max(e0 - b0, 1);

    float4 a2 = make_float4(0.f, 0.f, 0.f, 0.f);
    int b1 = rp_out[node], e1 = rp_out[node + 1];
    for (int e = b1; e < e1; ++e) {
        const float4 v = *reinterpret_cast<const float4*>(&TMP[(size_t)ci_out[e] * TMP_D + 256 + d]);
        a2.x += v.x; a2.y += v.y; a2.z += v.z; a2.w += v.w;
    }
    float s2 = 1.f / (float)max(e1 - b1, 1);

    const float4 rt = *reinterpret_cast<const float4*>(&TMP[(size_t)node * TMP_D + 512 + d]);
    const float4 bb = *reinterpret_cast<const float4*>(&br[d]);
    float o[4];
    o[0] = fmaxf(rt.x + bb.x + a1.x * s1 + a2.x * s2, 0.f);
    o[1] = fmaxf(rt.y + bb.y + a1.y * s1 + a2.y * s2, 0.f);
    o[2] = fmaxf(rt.z + bb.z + a1.z * s1 + a2.z * s2, 0.f);
    o[3] = fmaxf(rt.w + bb.w + a1.w * s1 + a2.w * s2, 0.f);
    short h[4], l[4];
    #pragma unroll
    for (int q = 0; q < 4; ++q) splitf(o[q], h[q], l[q]);
    *reinterpret_cast<short4*>(&CAThi[(size_t)node * CAT_D + catoff + d]) = make_short4(h[0], h[1], h[2], h[3]);
    *reinterpret_cast<short4*>(&CATlo[(size_t)node * CAT_D + catoff + d]) = make_short4(l[0], l[1], l[2], l[3]);
}

// row L2 normalization -> split bf16; one wave per row
__global__ __launch_bounds__(256) void l2norm_kernel(const float* __restrict__ in,
                                                     short* __restrict__ outhi,
                                                     short* __restrict__ outlo, int N)
{
    int row = blockIdx.x * 4 + (threadIdx.x >> 6);
    if (row >= N) return;
    int d = (threadIdx.x & 63) * 4;
    float4 v = *reinterpret_cast<const float4*>(&in[(size_t)row * D_H + d]);
    float s = v.x * v.x + v.y * v.y + v.z * v.z + v.w * v.w;
    #pragma unroll
    for (int off = 32; off; off >>= 1) s += __shfl_xor(s, off);
    float inv = 1.f / fmaxf(sqrtf(s), 1e-12f);
    float o[4] = {v.x * inv, v.y * inv, v.z * inv, v.w * inv};
    short h[4], l[4];
    #pragma unroll
    for (int q = 0; q < 4; ++q) splitf(o[q], h[q], l[q]);
    *reinterpret_cast<short4*>(&outhi[(size_t)row * D_H + d]) = make_short4(h[0], h[1], h[2], h[3]);
    *reinterpret_cast<short4*>(&outlo[(size_t)row * D_H + d]) = make_short4(l[0], l[1], l[2], l[3]);
}

// ---------------------------------------------------------------------------
// Sinkhorn passes. colsum: tsum[j] += sum_i r_i*s0[i][j] over 32-row chunk.
// ---------------------------------------------------------------------------
template<bool FIRST>
__global__ __launch_bounds__(256) void colsum_kernel(
    const float* __restrict__ s0, const float* __restrict__ r, float* __restrict__ tsum)
{
    int j4 = blockIdx.x * 256 + threadIdx.x;   // cols j4*4 .. +3
    int i0 = blockIdx.y * 32;
    int iend = min(i0 + 32, NS_N);
    float4 s = make_float4(0.f, 0.f, 0.f, 0.f);
    for (int i = i0; i < iend; ++i) {
        float ri = FIRST ? 1.f : r[i];
        const float4 v = *reinterpret_cast<const float4*>(&s0[(size_t)i * NT_N + j4 * 4]);
        s.x += ri * v.x; s.y += ri * v.y; s.z += ri * v.z; s.w += ri * v.w;
    }
    atomicAdd(&tsum[j4 * 4 + 0], s.x);
    atomicAdd(&tsum[j4 * 4 + 1], s.y);
    atomicAdd(&tsum[j4 * 4 + 2], s.z);
    atomicAdd(&tsum[j4 * 4 + 3], s.w);
}

// rowsum: c_j = 1/(tsum_j + NDUM*dummyv*rd_prev) inline;
// real rows: r_i = 1/sum_j s0_ij*c_j; block NS_N: rd_new = 1/(dummyv*sum_j c_j).
// Also zeroes tsumNext; FUSE_OUT: write out[i][j] = r_i*s0_ij*c_j.
template<bool FIRST, bool FUSE_OUT>
__global__ __launch_bounds__(256) void rowsum_kernel(
    const float* __restrict__ s0, const float* __restrict__ tsum,
    const float* __restrict__ rdR, float* __restrict__ rdW,
    float* __restrict__ r, float* __restrict__ tsumNext,
    float* __restrict__ out, float dummyv)
{
    int i = blockIdx.x;
    int t = threadIdx.x;
    if (i < 16) tsumNext[i * 256 + t] = 0.f;     // zero next tsum buffer
    float rdv = FIRST ? 1.f : rdR[0];
    float dd = (float)NDUM * dummyv * rdv;
    float s = 0.f;
    if (i < NS_N) {
        for (int j4 = t; j4 < NT_N / 4; j4 += 256) {
            const float4 v = *reinterpret_cast<const float4*>(&s0[(size_t)i * NT_N + j4 * 4]);
            const float4 ts = *reinterpret_cast<const float4*>(&tsum[j4 * 4]);
            s += v.x / (ts.x + dd) + v.y / (ts.y + dd) + v.z / (ts.z + dd) + v.w / (ts.w + dd);
        }
    } else {
        for (int j = t; j < NT_N; j += 256) s += 1.f / (tsum[j] + dd);
    }
    #pragma unroll
    for (int off = 32; off; off >>= 1) s += __shfl_xor(s, off);
    __shared__ float ws[4];
    __shared__ float ri_sh;
    if ((t & 63) == 0) ws[t >> 6] = s;
    __syncthreads();
    if (t == 0) {
        float tot = ws[0] + ws[1] + ws[2] + ws[3];
        if (i < NS_N) { r[i] = 1.f / tot; ri_sh = 1.f / tot; }
        else rdW[0] = 1.f / (dummyv * tot);
    }
    if (FUSE_OUT) {
        __syncthreads();
        if (i < NS_N) {
            float ri = ri_sh;
            for (int j4 = t; j4 < NT_N / 4; j4 += 256) {
                const float4 v = *reinterpret_cast<const float4*>(&s0[(size_t)i * NT_N + j4 * 4]);
                const float4 ts = *reinterpret_cast<const float4*>(&tsum[j4 * 4]);
                float4 o = make_float4(ri * v.x / (ts.x + dd), ri * v.y / (ts.y + dd),
                                       ri * v.z / (ts.z + dd), ri * v.w / (ts.w + dd));
                *reinterpret_cast<float4*>(&out[(size_t)i * NT_N + j4 * 4]) = o;
            }
        }
    }
}

extern "C" void kernel_launch(void* const* d_in, const int* in_sizes, int n_in,
                              void* d_out, int out_size, void* d_ws, size_t ws_size,
                              hipStream_t stream)
{
    const float* x_s = (const float*)d_in[0];
    const float* x_t = (const float*)d_in[1];
    const int* edges = (const int*)d_in[2];
    const int* edget = (const int*)d_in[3];
    const float* W1[3] = {(const float*)d_in[4], (const float*)d_in[8], (const float*)d_in[12]};
    const float* W2[3] = {(const float*)d_in[5], (const float*)d_in[9], (const float*)d_in[13]};
    const float* Wr[3] = {(const float*)d_in[6], (const float*)d_in[10], (const float*)d_in[14]};
    const float* br[3] = {(const float*)d_in[7], (const float*)d_in[11], (const float*)d_in[15]};
    const float* final_w = (const float*)d_in[16];
    const float* final_b = (const float*)d_in[17];
    float* out = (float*)d_out;

    // ---- workspace layout (float units; keep 16B alignment: all offsets even*4) ----
    float* W = (float*)d_ws;
    size_t off = 0;
    float* S0 = W + off;  off += (size_t)NS_N * NT_N;                 // 16.38M
    float* TMP = W + off; off += (size_t)NTOT * TMP_D;                // 6.22M
    short* CAThi = (short*)(W + off); off += (size_t)NTOT * CAT_D / 2;
    short* CATlo = (short*)(W + off); off += (size_t)NTOT * CAT_D / 2;
    const int fan[3] = {D_IN, D_H, D_H};
    short* WThi[3]; short* WTlo[3];
    for (int l = 0; l < 3; ++l) {
        WThi[l] = (short*)(W + off); off += (size_t)TMP_D * fan[l] / 2;
        WTlo[l] = (short*)(W + off); off += (size_t)TMP_D * fan[l] / 2;
    }
    short* WFhi = (short*)(W + off); off += (size_t)D_H * CAT_D / 2;
    short* WFlo = (short*)(W + off); off += (size_t)D_H * CAT_D / 2;
    float* RVEC = W + off; off += NS_N;
    float* RD   = W + off; off += 8;           // rd double buffer
    // contiguous zero-init region: TSA, CNT_IN, CNT_OUT
    float* TSA  = W + off; off += NT_N;
    int* CNT_IN  = (int*)(W + off); off += NTOT;
    int* CNT_OUT = (int*)(W + off); off += NTOT;
    float* TSB  = W + off; off += NT_N;
    int* RP_IN   = (int*)(W + off); off += NTOT + 1;
    int* RP_OUT  = (int*)(W + off); off += NTOT + 3;
    int* CUR_IN  = (int*)(W + off); off += NTOT;
    int* CUR_OUT = (int*)(W + off); off += NTOT;
    int* CI_IN   = (int*)(W + off); off += ETOT;
    int* CI_OUT  = (int*)(W + off); off += ETOT;
    float* HFIN = TMP;                                        // [NTOT][256] f32
    short* HNhi = (short*)(TMP + (size_t)NTOT * D_H);         // [NTOT][256] bf16
    short* HNlo = (short*)(TMP + (size_t)NTOT * D_H + (size_t)NTOT * D_H / 2);

    const int cat_off[4] = {0, 128, 384, 640};

    // ---- single fused zero-init (TSA + both CNT arrays) ----
    hipMemsetAsync(TSA, 0, (NT_N + 2 * NTOT) * sizeof(int), stream);

    // ---- weight transpose+split: 4 launches ----
    for (int l = 0; l < 3; ++l)
        wsplit3_kernel<<<(fan[l] * TMP_D + 255) / 256, 256, 0, stream>>>(
            W1[l], W2[l], Wr[l], WThi[l], WTlo[l], fan[l]);
    wsplitT_kernel<<<(CAT_D * D_H + 255) / 256, 256, 0, stream>>>(final_w, WFhi, WFlo, CAT_D, D_H);

    // ---- CSR build: count(1) + scan(1) + fill(1) ----
    {
        dim3 gc((ETOT + 255) / 256, 2);
        count2_kernel<<<gc, 256, 0, stream>>>(edges, edget, CNT_IN, CNT_OUT);
        scan2_kernel<<<2, 256, 0, stream>>>(CNT_IN, CNT_OUT, RP_IN, RP_OUT, CUR_IN, CUR_OUT);
        fill2_kernel<<<gc, 256, 0, stream>>>(edges, edget, CUR_IN, CUR_OUT, CI_IN, CI_OUT);
    }

    // ---- input copy (split) ----
    copy_x_kernel<<<NTOT, 128, 0, stream>>>(x_s, x_t, CAThi, CATlo);

    // ---- 3 GNN layers ----
    for (int l = 0; l < 3; ++l) {
        dim3 gg((NTOT + 127) / 128, TMP_D / 128);
        mfma_gemm_kernel<0><<<gg, 256, 0, stream>>>(
            CAThi + cat_off[l], CATlo + cat_off[l], WThi[l], WTlo[l], nullptr, TMP,
            NTOT, TMP_D, fan[l], CAT_D, fan[l], TMP_D);
        gather_combine_kernel<<<(NTOT + 3) / 4, 256, 0, stream>>>(
            TMP, RP_IN, CI_IN, RP_OUT, CI_OUT, br[l], CAThi, CATlo, cat_off[l + 1]);
    }

    // ---- final linear + l2norm ----
    {
        dim3 gf((NTOT + 127) / 128, D_H / 128);
        mfma_gemm_kernel<1><<<gf, 256, 0, stream>>>(
            CAThi, CATlo, WFhi, WFlo, final_b, HFIN, NTOT, D_H, CAT_D, CAT_D, CAT_D, D_H);
        l2norm_kernel<<<(NTOT + 3) / 4, 256, 0, stream>>>(HFIN, HNhi, HNlo, NTOT);
    }

    // ---- match matrix: s0 = exp(ALPHA*(HNS @ HNT^T + EPS)), real rows only ----
    {
        dim3 gm((NS_N + 127) / 128, NT_N / 128);
        mfma_gemm_kernel<2><<<gm, 256, 0, stream>>>(
            HNhi, HNlo, HNhi + (size_t)NS_N * D_H, HNlo + (size_t)NS_N * D_H, nullptr, S0,
            NS_N, NT_N, D_H, D_H, D_H, NT_N);
    }

    // ---- Sinkhorn: 5 (col,row) pairs; recip folded into rowsum; out fused ----
    const float dummyv = expf(ALPHA_F * (EPS_F + EPS_F));
    dim3 gcs(NT_N / 1024, (NS_N + 31) / 32);
    // p=0: tsumA; rd init implicit (FIRST)
    colsum_kernel<true><<<gcs, 256, 0, stream>>>(S0, nullptr, TSA);
    rowsum_kernel<true, false><<<NS_N + 1, 256, 0, stream>>>(
        S0, TSA, nullptr, &RD[0], RVEC, TSB, nullptr, dummyv);
    // p=1..3
    colsum_kernel<false><<<gcs, 256, 0, stream>>>(S0, RVEC, TSB);
    rowsum_kernel<false, false><<<NS_N + 1, 256, 0, stream>>>(
        S0, TSB, &RD[0], &RD[1], RVEC, TSA, nullptr, dummyv);
    colsum_kernel<false><<<gcs, 256, 0, stream>>>(S0, RVEC, TSA);
    rowsum_kernel<false, false><<<NS_N + 1, 256, 0, stream>>>(
        S0, TSA, &RD[1], &RD[0], RVEC, TSB, nullptr, dummyv);
    colsum_kernel<false><<<gcs, 256, 0, stream>>>(S0, RVEC, TSB);
    rowsum_kernel<false, false><<<NS_N + 1, 256, 0, stream>>>(
        S0, TSB, &RD[0], &RD[1], RVEC, TSA, nullptr, dummyv);
    // p=4: fused output
    colsum_kernel<false><<<gcs, 256, 0, stream>>>(S0, RVEC, TSA);
    rowsum_kernel<false, true><<<NS_N + 1, 256, 0, stream>>>(
        S0, TSA, &RD[1], &RD[0], RVEC, TSB, out, dummyv);
}

// Round 6
// 580.385 us; speedup vs baseline: 3.4875x; 1.0808x over previous
//
#include <hip/hip_runtime.h>
#include <hip/hip_bf16.h>

#define NS_N 4000
#define NT_N 4096
#define NTOT 8096
#define ES_E 64000
#define ET_E 65536
#define ETOT 129536
#define D_IN 128
#define D_H 256
#define CAT_D 896               // 128 + 3*256
#define TMP_D 768               // 3*256 fused layer GEMM output
#define NDUM (NT_N - NS_N)      // 96 dummy sinkhorn rows
#define ALPHA_F 20.0f
#define EPS_F 1e-10f

typedef __attribute__((ext_vector_type(8))) short bf16x8;
typedef __attribute__((ext_vector_type(4))) float f32x4;

__device__ inline short f2bf(float v) {
    __hip_bfloat16 b = __float2bfloat16(v);   // RNE
    return *reinterpret_cast<short*>(&b);
}
__device__ inline float bf2f(short s) {
    __hip_bfloat16 b = *reinterpret_cast<__hip_bfloat16*>(&s);
    return __bfloat162float(b);
}
__device__ inline void splitf(float v, short& hi, short& lo) {
    hi = f2bf(v);
    lo = f2bf(v - bf2f(hi));
}

typedef __attribute__((address_space(1))) const char gas_t;
typedef __attribute__((address_space(3))) char las_t;
__device__ inline void gload16(const short* g, short* l) {
    __builtin_amdgcn_global_load_lds((gas_t*)g, (las_t*)l, 16, 0, 0);
}

// ---------------------------------------------------------------------------
// Split-bf16 MFMA GEMM v3 (2-phase double-buffered, T3-minimum recipe):
// C[M,N]f32 = (Ahi+Alo)[M,K] @ (Bhi+Blo)^T[N,K].
// global_load_lds width-16, linear LDS [128][32] per half, 2 buffers (64KB).
// 256 thr = 4 waves (2x2), wave tile 64x64, block 128x128, K-step 32.
// EPI: 0=none, 1=+bias, 2=exp(ALPHA*(v+EPS)). COLSUM: atomic col-partials
// of the post-epilogue C tile into colacc (Sinkhorn it0 colsum, r=1).
// A/B rows clamped to M-1/N-1 (clamped rows never stored / never colsum'd).
// ---------------------------------------------------------------------------
template<int EPI, bool COLSUM>
__global__ __launch_bounds__(256) void mfma_gemm_kernel(
    const short* __restrict__ Ahi, const short* __restrict__ Alo,
    const short* __restrict__ Bhi, const short* __restrict__ Blo,
    const float* __restrict__ bias, float* __restrict__ C,
    float* __restrict__ colacc,
    int M, int N, int K, int lda, int ldb, int ldc)
{
    __shared__ __align__(16) short sAh[2][4096];   // [buf][row*32+seg], 8KB each
    __shared__ __align__(16) short sAl[2][4096];
    __shared__ __align__(16) short sBh[2][4096];
    __shared__ __align__(16) short sBl[2][4096];
    const int bm = blockIdx.x * 128;
    const int bn = blockIdx.y * 128;
    const int tid = threadIdx.x;
    const int lane = tid & 63, wv = tid >> 6;
    const int wr = wv >> 1, wc = wv & 1;
    const int lr = lane & 15, lg = lane >> 4;
    const int srow = lane >> 2, sseg = (lane & 3) * 8;

    f32x4 acc[4][4];
    #pragma unroll
    for (int i = 0; i < 4; ++i)
        #pragma unroll
        for (int j = 0; j < 4; ++j) {
            f32x4 z = {0.f, 0.f, 0.f, 0.f};
            acc[i][j] = z;
        }

    // wave-specialized staging: wave wv owns one of the 4 LDS arrays.
    // LDS dest is wave-uniform base + lane*16B; per-lane global src matches
    // row-major [row][32] exactly (proven addressing from round 4).
    auto stage = [&](int buf, int k0) {
        const short* src; short* dst; int rowbase, ld, maxrow;
        if (wv == 0)      { src = Ahi; dst = &sAh[buf][0]; rowbase = bm; ld = lda; maxrow = M - 1; }
        else if (wv == 1) { src = Alo; dst = &sAl[buf][0]; rowbase = bm; ld = lda; maxrow = M - 1; }
        else if (wv == 2) { src = Bhi; dst = &sBh[buf][0]; rowbase = bn; ld = ldb; maxrow = N - 1; }
        else              { src = Blo; dst = &sBl[buf][0]; rowbase = bn; ld = ldb; maxrow = N - 1; }
        #pragma unroll
        for (int q = 0; q < 8; ++q) {
            int gr = min(rowbase + q * 16 + srow, maxrow);
            gload16(src + (size_t)gr * ld + k0 + sseg, dst + q * 512);
        }
    };

    stage(0, 0);
    __syncthreads();
    int cur = 0;
    const int NTILES = K >> 5;
    for (int t0 = 0; t0 < NTILES; ++t0) {
        if (t0 + 1 < NTILES) stage(cur ^ 1, (t0 + 1) << 5);   // prefetch next tile
        bf16x8 ah[4], al[4], bh[4], bl[4];
        #pragma unroll
        for (int i = 0; i < 4; ++i) {
            int oa = (wr * 64 + i * 16 + lr) * 32 + lg * 8;
            ah[i] = *reinterpret_cast<const bf16x8*>(&sAh[cur][oa]);
            al[i] = *reinterpret_cast<const bf16x8*>(&sAl[cur][oa]);
            int ob = (wc * 64 + i * 16 + lr) * 32 + lg * 8;
            bh[i] = *reinterpret_cast<const bf16x8*>(&sBh[cur][ob]);
            bl[i] = *reinterpret_cast<const bf16x8*>(&sBl[cur][ob]);
        }
        #pragma unroll
        for (int i = 0; i < 4; ++i)
            #pragma unroll
            for (int j = 0; j < 4; ++j) {
                acc[i][j] = __builtin_amdgcn_mfma_f32_16x16x32_bf16(ah[i], bh[j], acc[i][j], 0, 0, 0);
                acc[i][j] = __builtin_amdgcn_mfma_f32_16x16x32_bf16(ah[i], bl[j], acc[i][j], 0, 0, 0);
                acc[i][j] = __builtin_amdgcn_mfma_f32_16x16x32_bf16(al[i], bh[j], acc[i][j], 0, 0, 0);
            }
        __syncthreads();   // compiler drains vmcnt+lgkm before s_barrier: prefetch landed
        cur ^= 1;
    }

    // epilogue: C/D layout col=lane&15, row=(lane>>4)*4+reg [m89-verified]
    float colp[4] = {0.f, 0.f, 0.f, 0.f};
    #pragma unroll
    for (int i = 0; i < 4; ++i) {
        #pragma unroll
        for (int j = 0; j < 4; ++j) {
            int col = bn + wc * 64 + j * 16 + lr;
            #pragma unroll
            for (int rr = 0; rr < 4; ++rr) {
                int row = bm + wr * 64 + i * 16 + lg * 4 + rr;
                if (row < M) {
                    float v = acc[i][j][rr];
                    if (EPI == 1) v += bias[col];
                    if (EPI == 2) v = expf(ALPHA_F * (v + EPS_F));
                    C[(size_t)row * ldc + col] = v;
                    if (COLSUM) colp[j] += v;
                }
            }
        }
    }
    if (COLSUM) {
        #pragma unroll
        for (int j = 0; j < 4; ++j) {
            float v = colp[j];
            v += __shfl_xor(v, 16);   // combine lg pairs
            v += __shfl_xor(v, 32);
            if (lg == 0) atomicAdd(&colacc[bn + wc * 64 + j * 16 + lr], v);
        }
    }
}

// ---------------------------------------------------------------------------
// prep: zero-init (TSA+CNT region) + all weight transpose/splits + copy_x
// ---------------------------------------------------------------------------
__global__ __launch_bounds__(256) void prep_kernel(
    const float* __restrict__ xs, const float* __restrict__ xt,
    const float* __restrict__ W1a, const float* __restrict__ W2a, const float* __restrict__ Wra,
    const float* __restrict__ W1b, const float* __restrict__ W2b, const float* __restrict__ Wrb,
    const float* __restrict__ W1c, const float* __restrict__ W2c, const float* __restrict__ Wrc,
    const float* __restrict__ WF,
    short* __restrict__ WThi0, short* __restrict__ WTlo0,
    short* __restrict__ WThi1, short* __restrict__ WTlo1,
    short* __restrict__ WThi2, short* __restrict__ WTlo2,
    short* __restrict__ WFhi, short* __restrict__ WFlo,
    short* __restrict__ CAThi, short* __restrict__ CATlo,
    int* __restrict__ zbase)
{
    int blk = blockIdx.x;
    const int t = threadIdx.x;
    if (blk < 80) {                       // zero TSA + CNT_IN + CNT_OUT
        int idx = blk * 256 + t;
        if (idx < NT_N + 2 * NTOT) zbase[idx] = 0;
        return;
    }
    blk -= 80;
    if (blk < 384 + 768 + 768) {          // layer weight splits
        const float *W1, *W2, *Wr; short *WThi, *WTlo; int K, idx;
        if (blk < 384)      { W1 = W1a; W2 = W2a; Wr = Wra; WThi = WThi0; WTlo = WTlo0; K = 128; idx = blk * 256 + t; }
        else if (blk < 1152){ W1 = W1b; W2 = W2b; Wr = Wrb; WThi = WThi1; WTlo = WTlo1; K = 256; idx = (blk - 384) * 256 + t; }
        else                { W1 = W1c; W2 = W2c; Wr = Wrc; WThi = WThi2; WTlo = WTlo2; K = 256; idx = (blk - 1152) * 256 + t; }
        int k = idx / TMP_D, c = idx % TMP_D;
        float v = (c < 256) ? W1[k * 256 + c]
                : (c < 512) ? W2[k * 256 + (c - 256)]
                            : Wr[k * 256 + (c - 512)];
        short hi, lo;
        splitf(v, hi, lo);
        WThi[(size_t)c * K + k] = hi;
        WTlo[(size_t)c * K + k] = lo;
        return;
    }
    blk -= 1920;
    if (blk < 896) {                      // final_w split: [896][256] -> WT[256][896]
        int idx = blk * 256 + t;
        int k = idx / D_H, n = idx % D_H;
        short hi, lo;
        splitf(WF[idx], hi, lo);
        WFhi[(size_t)n * CAT_D + k] = hi;
        WFlo[(size_t)n * CAT_D + k] = lo;
        return;
    }
    blk -= 896;
    {                                     // copy_x: 4048 blocks over NTOT*128
        int idx = blk * 256 + t;
        int i = idx >> 7, d = idx & 127;
        float v = (i < NS_N) ? xs[(size_t)i * D_IN + d] : xt[(size_t)(i - NS_N) * D_IN + d];
        short hi, lo;
        splitf(v, hi, lo);
        CAThi[(size_t)i * CAT_D + d] = hi;
        CATlo[(size_t)i * CAT_D + d] = lo;
    }
}

// ---------------------------------------------------------------------------
// CSR build: dir 0 = in-edges (key dst), dir 1 = out-edges (key src)
// ---------------------------------------------------------------------------
__global__ void count2_kernel(const int* __restrict__ es, const int* __restrict__ et,
                              int* __restrict__ cin, int* __restrict__ cout)
{
    int e = blockIdx.x * 256 + threadIdx.x;
    int dir = blockIdx.y;
    int* cnt = dir ? cout : cin;
    if (e < ES_E) {
        int key = dir ? es[e] : es[e + ES_E];
        atomicAdd(&cnt[key], 1);
    } else if (e < ETOT) {
        int e2 = e - ES_E;
        int key = dir ? et[e2] : et[e2 + ET_E];
        atomicAdd(&cnt[key + NS_N], 1);
    }
}

__global__ __launch_bounds__(256) void scan2_kernel(const int* __restrict__ cin,
                                                    const int* __restrict__ cout,
                                                    int* __restrict__ rpin, int* __restrict__ rpout,
                                                    int* __restrict__ curin, int* __restrict__ curout)
{
    const int* cnt = blockIdx.x ? cout : cin;
    int* rowptr = blockIdx.x ? rpout : rpin;
    int* cur = blockIdx.x ? curout : curin;
    __shared__ int sums[256];
    const int t = threadIdx.x;
    const int per = (NTOT + 255) / 256;
    const int lo = t * per, hi = min((t + 1) * per, NTOT);
    int s = 0;
    for (int i = lo; i < hi; ++i) s += cnt[i];
    sums[t] = s;
    __syncthreads();
    for (int off = 1; off < 256; off <<= 1) {
        int v = (t >= off) ? sums[t - off] : 0;
        __syncthreads();
        sums[t] += v;
        __syncthreads();
    }
    int base = (t == 0) ? 0 : sums[t - 1];
    for (int i = lo; i < hi; ++i) { rowptr[i] = base; cur[i] = base; base += cnt[i]; }
    if (t == 255) rowptr[NTOT] = base;
}

__global__ void fill2_kernel(const int* __restrict__ es, const int* __restrict__ et,
                             int* __restrict__ curin, int* __restrict__ curout,
                             int* __restrict__ ciin, int* __restrict__ ciout)
{
    int e = blockIdx.x * 256 + threadIdx.x;
    int dir = blockIdx.y;
    int* cur = dir ? curout : curin;
    int* ci = dir ? ciout : ciin;
    int key, val, off;
    if (e < ES_E) {
        key = dir ? es[e] : es[e + ES_E];
        val = dir ? es[e + ES_E] : es[e];
        off = 0;
    } else if (e < ETOT) {
        int e2 = e - ES_E;
        key = dir ? et[e2] : et[e2 + ET_E];
        val = dir ? et[e2 + ET_E] : et[e2];
        off = NS_N;
    } else return;
    int pos = atomicAdd(&cur[key + off], 1);
    ci[pos] = val + off;
}

// ---------------------------------------------------------------------------
// gather + mean + root + bias + relu -> split bf16 CAT slice
// ---------------------------------------------------------------------------
__global__ __launch_bounds__(256) void gather_combine_kernel(
    const float* __restrict__ TMP,
    const int* __restrict__ rp_in, const int* __restrict__ ci_in,
    const int* __restrict__ rp_out, const int* __restrict__ ci_out,
    const float* __restrict__ br, short* __restrict__ CAThi, short* __restrict__ CATlo,
    int catoff)
{
    int node = blockIdx.x * 4 + (threadIdx.x >> 6);
    if (node >= NTOT) return;
    int d = (threadIdx.x & 63) * 4;

    float4 a1 = make_float4(0.f, 0.f, 0.f, 0.f);
    int b0 = rp_in[node], e0 = rp_in[node + 1];
    for (int e = b0; e < e0; ++e) {
        const float4 v = *reinterpret_cast<const float4*>(&TMP[(size_t)ci_in[e] * TMP_D + d]);
        a1.x += v.x; a1.y += v.y; a1.z += v.z; a1.w += v.w;
    }
    float s1 = 1.f / (float)max(e0 - b0, 1);

    float4 a2 = make_float4(0.f, 0.f, 0.f, 0.f);
    int b1 = rp_out[node], e1 = rp_out[node + 1];
    for (int e = b1; e < e1; ++e) {
        const float4 v = *reinterpret_cast<const float4*>(&TMP[(size_t)ci_out[e] * TMP_D + 256 + d]);
        a2.x += v.x; a2.y += v.y; a2.z += v.z; a2.w += v.w;
    }
    float s2 = 1.f / (float)max(e1 - b1, 1);

    const float4 rt = *reinterpret_cast<const float4*>(&TMP[(size_t)node * TMP_D + 512 + d]);
    const float4 bb = *reinterpret_cast<const float4*>(&br[d]);
    float o[4];
    o[0] = fmaxf(rt.x + bb.x + a1.x * s1 + a2.x * s2, 0.f);
    o[1] = fmaxf(rt.y + bb.y + a1.y * s1 + a2.y * s2, 0.f);
    o[2] = fmaxf(rt.z + bb.z + a1.z * s1 + a2.z * s2, 0.f);
    o[3] = fmaxf(rt.w + bb.w + a1.w * s1 + a2.w * s2, 0.f);
    short h[4], l[4];
    #pragma unroll
    for (int q = 0; q < 4; ++q) splitf(o[q], h[q], l[q]);
    *reinterpret_cast<short4*>(&CAThi[(size_t)node * CAT_D + catoff + d]) = make_short4(h[0], h[1], h[2], h[3]);
    *reinterpret_cast<short4*>(&CATlo[(size_t)node * CAT_D + catoff + d]) = make_short4(l[0], l[1], l[2], l[3]);
}

// row L2 normalization -> split bf16; one wave per row
__global__ __launch_bounds__(256) void l2norm_kernel(const float* __restrict__ in,
                                                     short* __restrict__ outhi,
                                                     short* __restrict__ outlo, int N)
{
    int row = blockIdx.x * 4 + (threadIdx.x >> 6);
    if (row >= N) return;
    int d = (threadIdx.x & 63) * 4;
    float4 v = *reinterpret_cast<const float4*>(&in[(size_t)row * D_H + d]);
    float s = v.x * v.x + v.y * v.y + v.z * v.z + v.w * v.w;
    #pragma unroll
    for (int off = 32; off; off >>= 1) s += __shfl_xor(s, off);
    float inv = 1.f / fmaxf(sqrtf(s), 1e-12f);
    float o[4] = {v.x * inv, v.y * inv, v.z * inv, v.w * inv};
    short h[4], l[4];
    #pragma unroll
    for (int q = 0; q < 4; ++q) splitf(o[q], h[q], l[q]);
    *reinterpret_cast<short4*>(&outhi[(size_t)row * D_H + d]) = make_short4(h[0], h[1], h[2], h[3]);
    *reinterpret_cast<short4*>(&outlo[(size_t)row * D_H + d]) = make_short4(l[0], l[1], l[2], l[3]);
}

// ---------------------------------------------------------------------------
// Sinkhorn passes (separate dispatches; proven structure from round 4).
// colsum: tsum[j] += sum_i r_i*s0[i][j] over 32-row chunk.
// ---------------------------------------------------------------------------
__global__ __launch_bounds__(256) void colsum_kernel(
    const float* __restrict__ s0, const float* __restrict__ r, float* __restrict__ tsum)
{
    int j4 = blockIdx.x * 256 + threadIdx.x;   // cols j4*4 .. +3
    int i0 = blockIdx.y * 32;
    int iend = min(i0 + 32, NS_N);
    float4 s = make_float4(0.f, 0.f, 0.f, 0.f);
    for (int i = i0; i < iend; ++i) {
        float ri = r[i];
        const float4 v = *reinterpret_cast<const float4*>(&s0[(size_t)i * NT_N + j4 * 4]);
        s.x += ri * v.x; s.y += ri * v.y; s.z += ri * v.z; s.w += ri * v.w;
    }
    atomicAdd(&tsum[j4 * 4 + 0], s.x);
    atomicAdd(&tsum[j4 * 4 + 1], s.y);
    atomicAdd(&tsum[j4 * 4 + 2], s.z);
    atomicAdd(&tsum[j4 * 4 + 3], s.w);
}

// rowsum: c_j = 1/(tsum_j + NDUM*dummyv*rd_prev) inline;
// real rows: r_i = 1/sum_j s0_ij*c_j; block NS_N: rd_new = 1/(dummyv*sum_j c_j).
// Also zeroes tsumNext; FUSE_OUT: write out[i][j] = r_i*s0_ij*c_j.
template<bool FIRST, bool FUSE_OUT>
__global__ __launch_bounds__(256) void rowsum_kernel(
    const float* __restrict__ s0, const float* __restrict__ tsum,
    const float* __restrict__ rdR, float* __restrict__ rdW,
    float* __restrict__ r, float* __restrict__ tsumNext,
    float* __restrict__ out, float dummyv)
{
    int i = blockIdx.x;
    int t = threadIdx.x;
    if (i < 16) tsumNext[i * 256 + t] = 0.f;     // zero next tsum buffer
    float rdv = FIRST ? 1.f : rdR[0];
    float dd = (float)NDUM * dummyv * rdv;
    float s = 0.f;
    if (i < NS_N) {
        for (int j4 = t; j4 < NT_N / 4; j4 += 256) {
            const float4 v = *reinterpret_cast<const float4*>(&s0[(size_t)i * NT_N + j4 * 4]);
            const float4 ts = *reinterpret_cast<const float4*>(&tsum[j4 * 4]);
            s += v.x / (ts.x + dd) + v.y / (ts.y + dd) + v.z / (ts.z + dd) + v.w / (ts.w + dd);
        }
    } else {
        for (int j = t; j < NT_N; j += 256) s += 1.f / (tsum[j] + dd);
    }
    #pragma unroll
    for (int off = 32; off; off >>= 1) s += __shfl_xor(s, off);
    __shared__ float ws[4];
    __shared__ float ri_sh;
    if ((t & 63) == 0) ws[t >> 6] = s;
    __syncthreads();
    if (t == 0) {
        float tot = ws[0] + ws[1] + ws[2] + ws[3];
        if (i < NS_N) { r[i] = 1.f / tot; ri_sh = 1.f / tot; }
        else rdW[0] = 1.f / (dummyv * tot);
    }
    if (FUSE_OUT) {
        __syncthreads();
        if (i < NS_N) {
            float ri = ri_sh;
            for (int j4 = t; j4 < NT_N / 4; j4 += 256) {
                const float4 v = *reinterpret_cast<const float4*>(&s0[(size_t)i * NT_N + j4 * 4]);
                const float4 ts = *reinterpret_cast<const float4*>(&tsum[j4 * 4]);
                float4 o = make_float4(ri * v.x / (ts.x + dd), ri * v.y / (ts.y + dd),
                                       ri * v.z / (ts.z + dd), ri * v.w / (ts.w + dd));
                *reinterpret_cast<float4*>(&out[(size_t)i * NT_N + j4 * 4]) = o;
            }
        }
    }
}

extern "C" void kernel_launch(void* const* d_in, const int* in_sizes, int n_in,
                              void* d_out, int out_size, void* d_ws, size_t ws_size,
                              hipStream_t stream)
{
    const float* x_s = (const float*)d_in[0];
    const float* x_t = (const float*)d_in[1];
    const int* edges = (const int*)d_in[2];
    const int* edget = (const int*)d_in[3];
    const float* W1[3] = {(const float*)d_in[4], (const float*)d_in[8], (const float*)d_in[12]};
    const float* W2[3] = {(const float*)d_in[5], (const float*)d_in[9], (const float*)d_in[13]};
    const float* Wr[3] = {(const float*)d_in[6], (const float*)d_in[10], (const float*)d_in[14]};
    const float* br[3] = {(const float*)d_in[7], (const float*)d_in[11], (const float*)d_in[15]};
    const float* final_w = (const float*)d_in[16];
    const float* final_b = (const float*)d_in[17];
    float* out = (float*)d_out;

    // ---- workspace layout (float units) ----
    float* W = (float*)d_ws;
    size_t off = 0;
    float* S0 = W + off;  off += (size_t)NS_N * NT_N;                 // 16.38M
    float* TMP = W + off; off += (size_t)NTOT * TMP_D;                // 6.22M
    short* CAThi = (short*)(W + off); off += (size_t)NTOT * CAT_D / 2;
    short* CATlo = (short*)(W + off); off += (size_t)NTOT * CAT_D / 2;
    const int fan[3] = {D_IN, D_H, D_H};
    short* WThi[3]; short* WTlo[3];
    for (int l = 0; l < 3; ++l) {
        WThi[l] = (short*)(W + off); off += (size_t)TMP_D * fan[l] / 2;
        WTlo[l] = (short*)(W + off); off += (size_t)TMP_D * fan[l] / 2;
    }
    short* WFhi = (short*)(W + off); off += (size_t)D_H * CAT_D / 2;
    short* WFlo = (short*)(W + off); off += (size_t)D_H * CAT_D / 2;
    float* RVEC = W + off; off += NS_N;
    float* RD   = W + off; off += 8;           // rd double buffer
    // contiguous zero-init region: TSA, CNT_IN, CNT_OUT (prep kernel zeroes)
    float* TSA  = W + off; off += NT_N;
    int* CNT_IN  = (int*)(W + off); off += NTOT;
    int* CNT_OUT = (int*)(W + off); off += NTOT;
    float* TSB  = W + off; off += NT_N;
    int* RP_IN   = (int*)(W + off); off += NTOT + 1;
    int* RP_OUT  = (int*)(W + off); off += NTOT + 3;
    int* CUR_IN  = (int*)(W + off); off += NTOT;
    int* CUR_OUT = (int*)(W + off); off += NTOT;
    int* CI_IN   = (int*)(W + off); off += ETOT;
    int* CI_OUT  = (int*)(W + off); off += ETOT;
    float* HFIN = TMP;                                        // [NTOT][256] f32
    short* HNhi = (short*)(TMP + (size_t)NTOT * D_H);         // [NTOT][256] bf16
    short* HNlo = (short*)(TMP + (size_t)NTOT * D_H + (size_t)NTOT * D_H / 2);

    const int cat_off[4] = {0, 128, 384, 640};

    // ---- prep: zero + weight splits + copy_x (one dispatch) ----
    prep_kernel<<<6944, 256, 0, stream>>>(
        x_s, x_t,
        W1[0], W2[0], Wr[0], W1[1], W2[1], Wr[1], W1[2], W2[2], Wr[2], final_w,
        WThi[0], WTlo[0], WThi[1], WTlo[1], WThi[2], WTlo[2], WFhi, WFlo,
        CAThi, CATlo, (int*)TSA);

    // ---- CSR build ----
    {
        dim3 gc((ETOT + 255) / 256, 2);
        count2_kernel<<<gc, 256, 0, stream>>>(edges, edget, CNT_IN, CNT_OUT);
        scan2_kernel<<<2, 256, 0, stream>>>(CNT_IN, CNT_OUT, RP_IN, RP_OUT, CUR_IN, CUR_OUT);
        fill2_kernel<<<gc, 256, 0, stream>>>(edges, edget, CUR_IN, CUR_OUT, CI_IN, CI_OUT);
    }

    // ---- 3 GNN layers ----
    for (int l = 0; l < 3; ++l) {
        dim3 gg((NTOT + 127) / 128, TMP_D / 128);
        mfma_gemm_kernel<0, false><<<gg, 256, 0, stream>>>(
            CAThi + cat_off[l], CATlo + cat_off[l], WThi[l], WTlo[l], nullptr, TMP, nullptr,
            NTOT, TMP_D, fan[l], CAT_D, fan[l], TMP_D);
        gather_combine_kernel<<<(NTOT + 3) / 4, 256, 0, stream>>>(
            TMP, RP_IN, CI_IN, RP_OUT, CI_OUT, br[l], CAThi, CATlo, cat_off[l + 1]);
    }

    // ---- final linear + l2norm ----
    {
        dim3 gf((NTOT + 127) / 128, D_H / 128);
        mfma_gemm_kernel<1, false><<<gf, 256, 0, stream>>>(
            CAThi, CATlo, WFhi, WFlo, final_b, HFIN, nullptr,
            NTOT, D_H, CAT_D, CAT_D, CAT_D, D_H);
        l2norm_kernel<<<(NTOT + 3) / 4, 256, 0, stream>>>(HFIN, HNhi, HNlo, NTOT);
    }

    // ---- match matrix + fused Sinkhorn it0 colsum (r=1) into TSA ----
    {
        dim3 gm((NS_N + 127) / 128, NT_N / 128);
        mfma_gemm_kernel<2, true><<<gm, 256, 0, stream>>>(
            HNhi, HNlo, HNhi + (size_t)NS_N * D_H, HNlo + (size_t)NS_N * D_H, nullptr, S0, TSA,
            NS_N, NT_N, D_H, D_H, D_H, NT_N);
    }

    // ---- Sinkhorn it1..it9 (separate dispatches; it0 col fused above) ----
    const float dummyv = expf(ALPHA_F * (EPS_F + EPS_F));
    dim3 gcs(NT_N / 1024, (NS_N + 31) / 32);
    // it1 (row): reads TSA, writes RVEC + rd[0], zeroes TSB
    rowsum_kernel<true, false><<<NS_N + 1, 256, 0, stream>>>(
        S0, TSA, nullptr, &RD[0], RVEC, TSB, nullptr, dummyv);
    // it2 (col) + it3 (row)
    colsum_kernel<<<gcs, 256, 0, stream>>>(S0, RVEC, TSB);
    rowsum_kernel<false, false><<<NS_N + 1, 256, 0, stream>>>(
        S0, TSB, &RD[0], &RD[1], RVEC, TSA, nullptr, dummyv);
    // it4 + it5
    colsum_kernel<<<gcs, 256, 0, stream>>>(S0, RVEC, TSA);
    rowsum_kernel<false, false><<<NS_N + 1, 256, 0, stream>>>(
        S0, TSA, &RD[1], &RD[0], RVEC, TSB, nullptr, dummyv);
    // it6 + it7
    colsum_kernel<<<gcs, 256, 0, stream>>>(S0, RVEC, TSB);
    rowsum_kernel<false, false><<<NS_N + 1, 256, 0, stream>>>(
        S0, TSB, &RD[0], &RD[1], RVEC, TSA, nullptr, dummyv);
    // it8 + it9 (fused output)
    colsum_kernel<<<gcs, 256, 0, stream>>>(S0, RVEC, TSA);
    rowsum_kernel<false, true><<<NS_N + 1, 256, 0, stream>>>(
        S0, TSA, &RD[1], &RD[0], RVEC, TSB, out, dummyv);
}